// Round 5
// baseline (5689.528 us; speedup 1.0000x reference)
//
#include <hip/hip_runtime.h>

#define N_NODES   50000
#define N_EDGES   800000
#define N_REL     6
#define N_LAYERS  8
#define DD        256
#define NUM_GRAPHS 512

#define NKEYS      (N_REL * N_NODES)
#define SCAN_T     256
#define SCAN_E     8
#define SCAN_CHUNK (SCAN_T * SCAN_E)
#define SCAN_NB    ((NKEYS + SCAN_CHUNK - 1) / SCAN_CHUNK)

typedef _Float16 h4 __attribute__((ext_vector_type(4)));
typedef _Float16 h8 __attribute__((ext_vector_type(8)));
typedef float    f4 __attribute__((ext_vector_type(4)));

__device__ __forceinline__ void atomAddF(float* p, float v) { unsafeAtomicAdd(p, v); }

// ---------------- encoder: h = x @ enc_W + enc_b, write hi/lo fp16 planes ---
__global__ __launch_bounds__(256) void enc_kernel(const float* __restrict__ x,
                                                  const float* __restrict__ W,
                                                  const float* __restrict__ b,
                                                  _Float16* __restrict__ Hhi,
                                                  _Float16* __restrict__ Hlo) {
    int n = blockIdx.x;
    int d = threadIdx.x;
    float s = b[d];
#pragma unroll
    for (int k = 0; k < 13; ++k) s = fmaf(x[n * 13 + k], W[k * 256 + d], s);
    const _Float16 hi = (_Float16)s;
    Hhi[(size_t)n * DD + d] = hi;
    Hlo[(size_t)n * DD + d] = (_Float16)(s - (float)hi);
}

// ------------- weight split+transpose: rel_W/root_W(+I) -> WT[L][n][1792] ---
__global__ __launch_bounds__(256) void wsplit_rel_kernel(const float* __restrict__ relW,
                                                         const float* __restrict__ rootW,
                                                         _Float16* __restrict__ wthi,
                                                         _Float16* __restrict__ wtlo) {
    const size_t id = (size_t)blockIdx.x * 256 + threadIdx.x;
    if (id >= (size_t)N_LAYERS * 7 * 256 * 256) return;
    const int k = (int)(id & 255);
    const int n = (int)((id >> 8) & 255);
    const int g = (int)((id >> 16) % 7);
    const int L = (int)((id >> 16) / 7);
    float w = (g < 6)
        ? relW[(((size_t)L * 6 + g) * 256 + k) * 256 + n]
        : rootW[((size_t)L * 256 + k) * 256 + n];
    if (g == 6 && k == n) w += 1.0f;  // fold skip: h@(root+I) = h@root + h
    const _Float16 hi = (_Float16)w;
    const size_t o = ((size_t)L * 256 + n) * 1792 + (size_t)g * 256 + k;
    wthi[o] = hi;
    wtlo[o] = (_Float16)(w - (float)hi);
}

// generic 256x256 [k][n] -> split planes [n][k]
__global__ __launch_bounds__(256) void wsplit_tr_kernel(const float* __restrict__ W,
                                                        _Float16* __restrict__ whi,
                                                        _Float16* __restrict__ wlo) {
    const int id = blockIdx.x * 256 + threadIdx.x;  // 65536
    const int k = id & 255, n = id >> 8;
    const float w = W[(size_t)k * 256 + n];
    const _Float16 hi = (_Float16)w;
    whi[(size_t)n * 256 + k] = hi;
    wlo[(size_t)n * 256 + k] = (_Float16)(w - (float)hi);
}

// ---------------- MFMA GEMM: C[M x 256] = A @ B, fp16 hi/lo 3-term split ----
// Block tile 64 x 256 (full row width), 4 waves of 64x64, grid.x covers M.
// A = [agg planes (K_agg, plane stride N_NODES*256) | h segment]; B planes [n][ldb].
// MODE 0: Cf = acc + bias                                         (fp32 out)
// MODE 1: v = acc + Cf; prelu; row-L2-norm -> Ohi/Olo planes      (fused finalize)
// MODE 2: relu(acc + bias) -> Ohi/Olo planes
// MODE 3: Cf += acc                                               (accumulate)
template <int MODE>
__global__ __launch_bounds__(256) void mfma_gemm(
    const _Float16* __restrict__ Ahi, const _Float16* __restrict__ Alo,
    const _Float16* __restrict__ Hhi, const _Float16* __restrict__ Hlo,
    const _Float16* __restrict__ Bhi, const _Float16* __restrict__ Blo,
    int ldb, int boff_agg, int boff_h, int K_agg, int K_tot,
    float* __restrict__ Cf, _Float16* __restrict__ Ohi, _Float16* __restrict__ Olo,
    const float* __restrict__ bias, const float* __restrict__ pa, int M) {
    __shared__ float sh[4][64];
    const int lane = threadIdx.x & 63;
    const int wave = threadIdx.x >> 6;
    const int lm = lane & 15, lq = lane >> 4;
    const int mb  = blockIdx.x * 64;
    const int n0w = wave * 64;

    f4 acc[4][4];
#pragma unroll
    for (int i = 0; i < 4; ++i)
#pragma unroll
        for (int j = 0; j < 4; ++j) acc[i][j] = (f4){0.f, 0.f, 0.f, 0.f};

    for (int k0 = 0; k0 < K_tot; k0 += 32) {
        const _Float16 *pAh, *pAl;
        int acol, bcol;
        if (k0 < K_agg) {
            const size_t pb = (size_t)(k0 >> 8) * (size_t)N_NODES * DD;
            pAh = Ahi + pb; pAl = Alo + pb;
            acol = k0 & 255;
            bcol = boff_agg + k0;
        } else {
            pAh = Hhi; pAl = Hlo;
            acol = k0 - K_agg;
            bcol = boff_h + (k0 - K_agg);
        }
        h8 ah[4], al[4], bh[4], bl[4];
#pragma unroll
        for (int j = 0; j < 4; ++j) {
            const size_t bo = (size_t)(n0w + j * 16 + lm) * ldb + bcol + lq * 8;
            bh[j] = *(const h8*)(Bhi + bo);
            bl[j] = *(const h8*)(Blo + bo);
        }
#pragma unroll
        for (int i = 0; i < 4; ++i) {
            int row = mb + i * 16 + lm;
            if (row >= M) row = M - 1;
            const size_t ao = (size_t)row * DD + acol + lq * 8;
            ah[i] = *(const h8*)(pAh + ao);
            al[i] = *(const h8*)(pAl + ao);
        }
#pragma unroll
        for (int i = 0; i < 4; ++i)
#pragma unroll
            for (int j = 0; j < 4; ++j) {
                acc[i][j] = __builtin_amdgcn_mfma_f32_16x16x32_f16(ah[i], bh[j], acc[i][j], 0, 0, 0);
                acc[i][j] = __builtin_amdgcn_mfma_f32_16x16x32_f16(ah[i], bl[j], acc[i][j], 0, 0, 0);
                acc[i][j] = __builtin_amdgcn_mfma_f32_16x16x32_f16(al[i], bh[j], acc[i][j], 0, 0, 0);
            }
    }

    if (MODE == 0) {
#pragma unroll
        for (int i = 0; i < 4; ++i)
#pragma unroll
            for (int r = 0; r < 4; ++r) {
                const int row = mb + i * 16 + lq * 4 + r;
                if (row >= M) continue;
#pragma unroll
                for (int j = 0; j < 4; ++j) {
                    const int col = n0w + j * 16 + lm;
                    Cf[(size_t)row * DD + col] = acc[i][j][r] + bias[col];
                }
            }
    } else if (MODE == 3) {
#pragma unroll
        for (int i = 0; i < 4; ++i)
#pragma unroll
            for (int r = 0; r < 4; ++r) {
                const int row = mb + i * 16 + lq * 4 + r;
                if (row >= M) continue;
#pragma unroll
                for (int j = 0; j < 4; ++j) {
                    const int col = n0w + j * 16 + lm;
                    Cf[(size_t)row * DD + col] += acc[i][j][r];
                }
            }
    } else if (MODE == 2) {
#pragma unroll
        for (int i = 0; i < 4; ++i)
#pragma unroll
            for (int r = 0; r < 4; ++r) {
                const int row = mb + i * 16 + lq * 4 + r;
                if (row >= M) continue;
#pragma unroll
                for (int j = 0; j < 4; ++j) {
                    const int col = n0w + j * 16 + lm;
                    const float v = fmaxf(acc[i][j][r] + bias[col], 0.f);
                    const _Float16 hi = (_Float16)v;
                    const size_t idx = (size_t)row * DD + col;
                    Ohi[idx] = hi;
                    Olo[idx] = (_Float16)(v - (float)hi);
                }
            }
    } else {  // MODE 1: add Cf, PReLU, row L2-norm, write planes
        const float a = pa[0];
        float ssr[4][4];
#pragma unroll
        for (int i = 0; i < 4; ++i)
#pragma unroll
            for (int r = 0; r < 4; ++r) {
                const int row = mb + i * 16 + lq * 4 + r;
                float ss = 0.f;
#pragma unroll
                for (int j = 0; j < 4; ++j) {
                    const int col = n0w + j * 16 + lm;
                    float v = acc[i][j][r];
                    if (row < M) v += Cf[(size_t)row * DD + col];
                    v = v > 0.f ? v : a * v;
                    acc[i][j][r] = v;
                    ss = fmaf(v, v, ss);
                }
                ss += __shfl_xor(ss, 1, 64);
                ss += __shfl_xor(ss, 2, 64);
                ss += __shfl_xor(ss, 4, 64);
                ss += __shfl_xor(ss, 8, 64);
                ssr[i][r] = ss;
            }
        if (lm == 0) {
#pragma unroll
            for (int i = 0; i < 4; ++i)
#pragma unroll
                for (int r = 0; r < 4; ++r) sh[wave][i * 16 + lq * 4 + r] = ssr[i][r];
        }
        __syncthreads();
#pragma unroll
        for (int i = 0; i < 4; ++i)
#pragma unroll
            for (int r = 0; r < 4; ++r) {
                const int rl  = i * 16 + lq * 4 + r;
                const int row = mb + rl;
                if (row >= M) continue;
                const float tot = sh[0][rl] + sh[1][rl] + sh[2][rl] + sh[3][rl];
                const float inv = 1.0f / fmaxf(sqrtf(tot), 1e-12f);
#pragma unroll
                for (int j = 0; j < 4; ++j) {
                    const int col = n0w + j * 16 + lm;
                    const float v = acc[i][j][r] * inv;
                    const _Float16 hi = (_Float16)v;
                    const size_t idx = (size_t)row * DD + col;
                    Ohi[idx] = hi;
                    Olo[idx] = (_Float16)(v - (float)hi);
                }
            }
    }
}

// ================= CSR build: counting sort by key = rel*N_NODES + dst ======
__global__ __launch_bounds__(256) void hist_kernel(const int* __restrict__ dst,
                                                   const int* __restrict__ etype,
                                                   int* __restrict__ cnt) {
    const int e = blockIdx.x * 256 + threadIdx.x;
    if (e >= N_EDGES) return;
    atomicAdd(&cnt[etype[e] * N_NODES + dst[e]], 1);
}

__global__ __launch_bounds__(SCAN_T) void scan1_kernel(const int* __restrict__ cnt,
                                                       int* __restrict__ off,
                                                       int* __restrict__ bsum) {
    __shared__ int sh[SCAN_T];
    const int b = blockIdx.x, t = threadIdx.x;
    const int base = b * SCAN_CHUNK + t * SCAN_E;
    int pre[SCAN_E];
    int s = 0;
#pragma unroll
    for (int i = 0; i < SCAN_E; ++i) {
        const int x = (base + i < NKEYS) ? cnt[base + i] : 0;
        pre[i] = s;
        s += x;
    }
    sh[t] = s;
    __syncthreads();
    for (int d = 1; d < SCAN_T; d <<= 1) {
        const int x = (t >= d) ? sh[t - d] : 0;
        __syncthreads();
        sh[t] += x;
        __syncthreads();
    }
    const int toff = (t == 0) ? 0 : sh[t - 1];
#pragma unroll
    for (int i = 0; i < SCAN_E; ++i)
        if (base + i < NKEYS) off[base + i] = toff + pre[i];
    if (t == SCAN_T - 1) bsum[b] = sh[SCAN_T - 1];
}

__global__ __launch_bounds__(SCAN_T) void scan2_kernel(int* __restrict__ bsum, int n) {
    __shared__ int sh[SCAN_T];
    const int t = threadIdx.x;
    const int base = t * SCAN_E;
    int pre[SCAN_E];
    int s = 0;
#pragma unroll
    for (int i = 0; i < SCAN_E; ++i) {
        const int x = (base + i < n) ? bsum[base + i] : 0;
        pre[i] = s;
        s += x;
    }
    sh[t] = s;
    __syncthreads();
    for (int d = 1; d < SCAN_T; d <<= 1) {
        const int x = (t >= d) ? sh[t - d] : 0;
        __syncthreads();
        sh[t] += x;
        __syncthreads();
    }
    const int toff = (t == 0) ? 0 : sh[t - 1];
#pragma unroll
    for (int i = 0; i < SCAN_E; ++i)
        if (base + i < n) bsum[base + i] = toff + pre[i];
}

__global__ __launch_bounds__(SCAN_T) void scan3_kernel(int* __restrict__ off,
                                                       const int* __restrict__ bsum) {
    const int b = blockIdx.x, t = threadIdx.x;
    const int add = bsum[b];
    const int base = b * SCAN_CHUNK + t * SCAN_E;
#pragma unroll
    for (int i = 0; i < SCAN_E; ++i)
        if (base + i < NKEYS) off[base + i] += add;
    if (b == 0 && t == 0) off[NKEYS] = N_EDGES;
}

__global__ __launch_bounds__(256) void csr_fill_kernel(const int* __restrict__ src,
                                                       const int* __restrict__ dst,
                                                       const int* __restrict__ etype,
                                                       int* __restrict__ cursor,
                                                       int* __restrict__ sorted_src) {
    const int e = blockIdx.x * 256 + threadIdx.x;
    if (e >= N_EDGES) return;
    const int key = etype[e] * N_NODES + dst[e];
    const int pos = atomicAdd(&cursor[key], 1);
    sorted_src[pos] = src[e];
}

// ---------- aggregation of h (hi+lo planes) for 2 relations -> agg planes ---
__global__ __launch_bounds__(256) void agg2_kernel(const _Float16* __restrict__ Hhi,
                                                   const _Float16* __restrict__ Hlo,
                                                   const int* __restrict__ off,
                                                   const int* __restrict__ isrc,
                                                   _Float16* __restrict__ agghi,
                                                   _Float16* __restrict__ agglo, int rel0) {
    const int node = blockIdx.x * 4 + (threadIdx.x >> 6);
    const int lane = threadIdx.x & 63;
    if (node >= N_NODES) return;
#pragma unroll
    for (int rl = 0; rl < 2; ++rl) {
        const int r = rel0 + rl;
        const int s0 = off[r * N_NODES + node];
        const int s1 = off[r * N_NODES + node + 1];
        float a0 = 0.f, a1 = 0.f, a2 = 0.f, a3 = 0.f;
        for (int e = s0; e < s1; ++e) {
            const int s = isrc[e];
            const h4 vh = *(const h4*)(Hhi + (size_t)s * DD + lane * 4);
            const h4 vl = *(const h4*)(Hlo + (size_t)s * DD + lane * 4);
            a0 += (float)vh[0] + (float)vl[0];
            a1 += (float)vh[1] + (float)vl[1];
            a2 += (float)vh[2] + (float)vl[2];
            a3 += (float)vh[3] + (float)vl[3];
        }
        h4 oh, ol;
        oh[0] = (_Float16)a0; ol[0] = (_Float16)(a0 - (float)oh[0]);
        oh[1] = (_Float16)a1; ol[1] = (_Float16)(a1 - (float)oh[1]);
        oh[2] = (_Float16)a2; ol[2] = (_Float16)(a2 - (float)oh[2]);
        oh[3] = (_Float16)a3; ol[3] = (_Float16)(a3 - (float)oh[3]);
        const size_t o = ((size_t)rl * N_NODES + node) * DD + lane * 4;
        *(h4*)(agghi + o) = oh;
        *(h4*)(agglo + o) = ol;
    }
}

// ---------------- fp32 tiled GEMM for small fc tail (relu epilogue) ---------
__global__ __launch_bounds__(256) void gemm128x64(const float* __restrict__ A,
                                                  const float* __restrict__ B,
                                                  float* __restrict__ C,
                                                  const float* __restrict__ bias,
                                                  int M, int N, int K) {
    __shared__ float As[16 * 132];
    __shared__ float Bs[16 * 68];
    const int t  = threadIdx.x;
    const int tx = t & 15;
    const int ty = t >> 4;
    const int m0 = blockIdx.x * 128;
    const int n0 = blockIdx.y * 64;
    const int arow = t >> 2;
    const int ak   = (t & 3) * 4;
    const int bk   = t >> 4;
    const int bc   = (t & 15) * 4;

    float acc[8][4];
#pragma unroll
    for (int i = 0; i < 8; ++i)
#pragma unroll
        for (int j = 0; j < 4; ++j) acc[i][j] = 0.f;

    for (int k0 = 0; k0 < K; k0 += 16) {
        float4 a0 = {0.f, 0.f, 0.f, 0.f}, a1 = {0.f, 0.f, 0.f, 0.f};
        const int r0 = m0 + arow, r1 = r0 + 64;
        if (r0 < M) a0 = *reinterpret_cast<const float4*>(A + (size_t)r0 * K + k0 + ak);
        if (r1 < M) a1 = *reinterpret_cast<const float4*>(A + (size_t)r1 * K + k0 + ak);
        const float4 bb = *reinterpret_cast<const float4*>(B + (size_t)(k0 + bk) * N + n0 + bc);
        __syncthreads();
        As[(ak + 0) * 132 + arow] = a0.x;
        As[(ak + 1) * 132 + arow] = a0.y;
        As[(ak + 2) * 132 + arow] = a0.z;
        As[(ak + 3) * 132 + arow] = a0.w;
        As[(ak + 0) * 132 + arow + 64] = a1.x;
        As[(ak + 1) * 132 + arow + 64] = a1.y;
        As[(ak + 2) * 132 + arow + 64] = a1.z;
        As[(ak + 3) * 132 + arow + 64] = a1.w;
        *reinterpret_cast<float4*>(&Bs[bk * 68 + bc]) = bb;
        __syncthreads();
#pragma unroll
        for (int k = 0; k < 16; ++k) {
            const float4 fa0 = *reinterpret_cast<const float4*>(&As[k * 132 + ty * 8]);
            const float4 fa1 = *reinterpret_cast<const float4*>(&As[k * 132 + ty * 8 + 4]);
            const float4 fb  = *reinterpret_cast<const float4*>(&Bs[k * 68 + tx * 4]);
            const float av[8] = {fa0.x, fa0.y, fa0.z, fa0.w, fa1.x, fa1.y, fa1.z, fa1.w};
            const float bv[4] = {fb.x, fb.y, fb.z, fb.w};
#pragma unroll
            for (int i = 0; i < 8; ++i)
#pragma unroll
                for (int j = 0; j < 4; ++j) acc[i][j] = fmaf(av[i], bv[j], acc[i][j]);
        }
    }
    const int row = m0 + ty * 8;
    const int col = n0 + tx * 4;
    const float4 bv = *reinterpret_cast<const float4*>(bias + col);
#pragma unroll
    for (int i = 0; i < 8; ++i) {
        const int m = row + i;
        if (m >= M) continue;
        float4 v = {acc[i][0], acc[i][1], acc[i][2], acc[i][3]};
        v.x = fmaxf(v.x + bv.x, 0.f); v.y = fmaxf(v.y + bv.y, 0.f);
        v.z = fmaxf(v.z + bv.z, 0.f); v.w = fmaxf(v.w + bv.w, 0.f);
        *reinterpret_cast<float4*>(C + (size_t)m * N + col) = v;
    }
}

// ---------------- pooled[batch[n]] += g[n]  (batch sorted) ------------------
__global__ __launch_bounds__(64) void pool_kernel(const float* __restrict__ g,
                                                  const int* __restrict__ batch,
                                                  float* __restrict__ pooled) {
    const int c     = threadIdx.x;
    const int start = blockIdx.x * 128;
    const int end   = min(start + 128, N_NODES);
    int cur = batch[start];
    float4 acc = {0.f, 0.f, 0.f, 0.f};
    for (int n = start; n < end; ++n) {
        const int bn = batch[n];
        if (bn != cur) {
            float* p = pooled + (size_t)cur * DD + c * 4;
            atomAddF(p + 0, acc.x); atomAddF(p + 1, acc.y);
            atomAddF(p + 2, acc.z); atomAddF(p + 3, acc.w);
            acc = {0.f, 0.f, 0.f, 0.f};
            cur = bn;
        }
        const float4 v = reinterpret_cast<const float4*>(g + (size_t)n * DD)[c];
        acc.x += v.x; acc.y += v.y; acc.z += v.z; acc.w += v.w;
    }
    float* p = pooled + (size_t)cur * DD + c * 4;
    atomAddF(p + 0, acc.x); atomAddF(p + 1, acc.y);
    atomAddF(p + 2, acc.z); atomAddF(p + 3, acc.w);
}

__global__ __launch_bounds__(64) void out_kernel(const float* __restrict__ z2,
                                                 const float* __restrict__ W,
                                                 const float* __restrict__ b,
                                                 float* __restrict__ out) {
    const int g = blockIdx.x;
    const int t = threadIdx.x;
    float s = 0.f;
#pragma unroll
    for (int j = 0; j < 8; ++j) s = fmaf(z2[(size_t)g * 512 + t + 64 * j], W[t + 64 * j], s);
#pragma unroll
    for (int off = 32; off; off >>= 1) s += __shfl_xor(s, off, 64);
    if (t == 0) {
        const float v = s + b[0];
        out[g] = v > 0.f ? v : 0.f;
    }
}

extern "C" void kernel_launch(void* const* d_in, const int* in_sizes, int n_in,
                              void* d_out, int out_size, void* d_ws, size_t ws_size,
                              hipStream_t stream) {
    const float* x       = (const float*)d_in[0];
    const int*   eidx    = (const int*)d_in[1];
    const int*   etype   = (const int*)d_in[2];
    const int*   batch   = (const int*)d_in[3];
    const float* enc_W   = (const float*)d_in[4];
    const float* enc_b   = (const float*)d_in[5];
    const float* prelu_a = (const float*)d_in[6];
    const float* rel_W   = (const float*)d_in[7];
    const float* root_W  = (const float*)d_in[8];
    const float* conv_b  = (const float*)d_in[9];
    const float* gp_W1   = (const float*)d_in[10];
    const float* gp_b1   = (const float*)d_in[11];
    const float* gp_W2   = (const float*)d_in[12];
    const float* gp_b2   = (const float*)d_in[13];
    const float* fc_W1   = (const float*)d_in[14];
    const float* fc_b1   = (const float*)d_in[15];
    const float* fc_W2   = (const float*)d_in[16];
    const float* fc_b2   = (const float*)d_in[17];
    const float* out_W   = (const float*)d_in[18];
    const float* out_b   = (const float*)d_in[19];
    float* out = (float*)d_out;

    // workspace arena — keep total < 256 MiB (R4's 277 MB crashed; R3's 226 MB ran)
    uint8_t* wp = (uint8_t*)d_ws;
    auto alloc = [&](size_t bytes) {
        void* r = (void*)wp;
        wp += (bytes + 255) & ~(size_t)255;
        return r;
    };
    float*    base   = (float*)alloc((size_t)N_NODES * DD * 4);          // 51.2 MB
    _Float16* Hhi    = (_Float16*)alloc((size_t)N_NODES * DD * 2);       // 25.6 MB
    _Float16* Hlo    = (_Float16*)alloc((size_t)N_NODES * DD * 2);       // 25.6 MB
    _Float16* agghi  = (_Float16*)alloc((size_t)2 * N_NODES * DD * 2);   // 51.2 MB
    _Float16* agglo  = (_Float16*)alloc((size_t)2 * N_NODES * DD * 2);   // 51.2 MB
    _Float16* wthi   = (_Float16*)alloc((size_t)N_LAYERS * 256 * 1792 * 2);  // 7.3 MB
    _Float16* wtlo   = (_Float16*)alloc((size_t)N_LAYERS * 256 * 1792 * 2);  // 7.3 MB
    _Float16* wtg1hi = (_Float16*)alloc((size_t)256 * 256 * 2);
    _Float16* wtg1lo = (_Float16*)alloc((size_t)256 * 256 * 2);
    _Float16* wtg2hi = (_Float16*)alloc((size_t)256 * 256 * 2);
    _Float16* wtg2lo = (_Float16*)alloc((size_t)256 * 256 * 2);
    float*    pooled = (float*)alloc((size_t)NUM_GRAPHS * DD * 4);
    float*    z1     = (float*)alloc((size_t)NUM_GRAPHS * 1024 * 4);
    float*    z2     = (float*)alloc((size_t)NUM_GRAPHS * 512 * 4);
    int*      ioff   = (int*)alloc((size_t)(NKEYS + 1) * 4);
    int*      icur   = (int*)alloc((size_t)NKEYS * 4);
    int*      ibsum  = (int*)alloc(256 * 4);
    int*      isrc   = (int*)alloc((size_t)N_EDGES * 4);
    // total ≈ 229 MB

    const int* src = eidx;
    const int* dst = eidx + N_EDGES;

    // ---- weight prep ----
    const size_t wtot = (size_t)N_LAYERS * 7 * 256 * 256;
    wsplit_rel_kernel<<<(int)((wtot + 255) / 256), 256, 0, stream>>>(rel_W, root_W, wthi, wtlo);
    wsplit_tr_kernel<<<256, 256, 0, stream>>>(gp_W1, wtg1hi, wtg1lo);
    wsplit_tr_kernel<<<256, 256, 0, stream>>>(gp_W2, wtg2hi, wtg2lo);

    // ---- CSR build ----
    hipMemsetAsync(icur, 0, (size_t)NKEYS * sizeof(int), stream);
    const int eb = (N_EDGES + 255) / 256;
    hist_kernel<<<eb, 256, 0, stream>>>(dst, etype, icur);
    scan1_kernel<<<SCAN_NB, SCAN_T, 0, stream>>>(icur, ioff, ibsum);
    scan2_kernel<<<1, SCAN_T, 0, stream>>>(ibsum, SCAN_NB);
    scan3_kernel<<<SCAN_NB, SCAN_T, 0, stream>>>(ioff, ibsum);
    hipMemcpyAsync(icur, ioff, (size_t)NKEYS * sizeof(int), hipMemcpyDeviceToDevice, stream);
    csr_fill_kernel<<<eb, 256, 0, stream>>>(src, dst, etype, icur, isrc);

    // ---- encoder ----
    enc_kernel<<<N_NODES, 256, 0, stream>>>(x, enc_W, enc_b, Hhi, Hlo);

    const int gemmb = (N_NODES + 63) / 64;  // 782
    const int nodeb = (N_NODES + 3) / 4;

    for (int L = 0; L < N_LAYERS; ++L) {
        const _Float16* Bh = wthi + (size_t)L * 256 * 1792;
        const _Float16* Bl = wtlo + (size_t)L * 256 * 1792;
        // chunk 1: rels 0,1 (K_agg=512) + root+I via h segment (K=256) + conv_b
        agg2_kernel<<<nodeb, 256, 0, stream>>>(Hhi, Hlo, ioff, isrc, agghi, agglo, 0);
        mfma_gemm<0><<<gemmb, 256, 0, stream>>>(agghi, agglo, Hhi, Hlo, Bh, Bl,
                                                1792, 0, 1536, 512, 768,
                                                base, nullptr, nullptr,
                                                conv_b + L * DD, nullptr, N_NODES);
        // chunk 2: rels 2,3 accumulate into base
        agg2_kernel<<<nodeb, 256, 0, stream>>>(Hhi, Hlo, ioff, isrc, agghi, agglo, 2);
        mfma_gemm<3><<<gemmb, 256, 0, stream>>>(agghi, agglo, Hhi, Hlo, Bh, Bl,
                                                1792, 512, 0, 512, 512,
                                                base, nullptr, nullptr,
                                                nullptr, nullptr, N_NODES);
        // chunk 3: rels 4,5 + add base + PReLU + L2-norm -> new h planes
        agg2_kernel<<<nodeb, 256, 0, stream>>>(Hhi, Hlo, ioff, isrc, agghi, agglo, 4);
        mfma_gemm<1><<<gemmb, 256, 0, stream>>>(agghi, agglo, Hhi, Hlo, Bh, Bl,
                                                1792, 1024, 0, 512, 512,
                                                base, Hhi, Hlo,
                                                nullptr, prelu_a, N_NODES);
    }

    // gp1 = relu(h @ gp_W1 + gp_b1) -> planes (reuse agg buffers)
    mfma_gemm<2><<<gemmb, 256, 0, stream>>>(nullptr, nullptr, Hhi, Hlo, wtg1hi, wtg1lo,
                                            256, 0, 0, 0, 256,
                                            nullptr, agghi, agglo, gp_b1, nullptr, N_NODES);
    // gp2 = gp1 @ gp_W2 + gp_b2 -> base (fp32)
    mfma_gemm<0><<<gemmb, 256, 0, stream>>>(agghi, agglo, nullptr, nullptr, wtg2hi, wtg2lo,
                                            256, 0, 0, 256, 256,
                                            base, nullptr, nullptr, gp_b2, nullptr, N_NODES);

    hipMemsetAsync(pooled, 0, (size_t)NUM_GRAPHS * DD * sizeof(float), stream);
    pool_kernel<<<(N_NODES + 127) / 128, 64, 0, stream>>>(base, batch, pooled);

    gemm128x64<<<dim3(4, 16), 256, 0, stream>>>(pooled, fc_W1, z1, fc_b1,
                                                NUM_GRAPHS, 1024, DD);
    gemm128x64<<<dim3(4, 8), 256, 0, stream>>>(z1, fc_W2, z2, fc_b2,
                                               NUM_GRAPHS, 512, 1024);
    out_kernel<<<NUM_GRAPHS, 64, 0, stream>>>(z2, out_W, out_b, out);
}

// Round 6
// 3701.993 us; speedup vs baseline: 1.5369x; 1.5369x over previous
//
#include <hip/hip_runtime.h>

#define N_NODES   50000
#define N_EDGES   800000
#define N_REL     6
#define N_LAYERS  8
#define DD        256
#define NUM_GRAPHS 512

#define NKEYS      (N_REL * N_NODES)
#define SCAN_T     256
#define SCAN_E     8
#define SCAN_CHUNK (SCAN_T * SCAN_E)
#define SCAN_NB    ((NKEYS + SCAN_CHUNK - 1) / SCAN_CHUNK)

typedef _Float16 h4 __attribute__((ext_vector_type(4)));
typedef _Float16 h8 __attribute__((ext_vector_type(8)));
typedef float    f4 __attribute__((ext_vector_type(4)));

__device__ __forceinline__ void atomAddF(float* p, float v) { unsafeAtomicAdd(p, v); }

// async global->LDS, 16B per lane. LDS ptr must be wave-uniform; global per-lane.
__device__ __forceinline__ void load_lds16(const void* g, void* l) {
    __builtin_amdgcn_global_load_lds(
        (const __attribute__((address_space(1))) uint32_t*)g,
        (__attribute__((address_space(3))) uint32_t*)l, 16, 0, 0);
}

// ---------------- encoder: h = x @ enc_W + enc_b, write hi/lo fp16 planes ---
__global__ __launch_bounds__(256) void enc_kernel(const float* __restrict__ x,
                                                  const float* __restrict__ W,
                                                  const float* __restrict__ b,
                                                  _Float16* __restrict__ Hhi,
                                                  _Float16* __restrict__ Hlo) {
    int n = blockIdx.x;
    int d = threadIdx.x;
    float s = b[d];
#pragma unroll
    for (int k = 0; k < 13; ++k) s = fmaf(x[n * 13 + k], W[k * 256 + d], s);
    const _Float16 hi = (_Float16)s;
    Hhi[(size_t)n * DD + d] = hi;
    Hlo[(size_t)n * DD + d] = (_Float16)(s - (float)hi);
}

// ------------- weight split+transpose: rel_W/root_W(+I) -> WT[L][n][1792] ---
__global__ __launch_bounds__(256) void wsplit_rel_kernel(const float* __restrict__ relW,
                                                         const float* __restrict__ rootW,
                                                         _Float16* __restrict__ wthi,
                                                         _Float16* __restrict__ wtlo) {
    const size_t id = (size_t)blockIdx.x * 256 + threadIdx.x;
    if (id >= (size_t)N_LAYERS * 7 * 256 * 256) return;
    const int k = (int)(id & 255);
    const int n = (int)((id >> 8) & 255);
    const int g = (int)((id >> 16) % 7);
    const int L = (int)((id >> 16) / 7);
    float w = (g < 6)
        ? relW[(((size_t)L * 6 + g) * 256 + k) * 256 + n]
        : rootW[((size_t)L * 256 + k) * 256 + n];
    if (g == 6 && k == n) w += 1.0f;  // fold skip: h@(root+I) = h@root + h
    const _Float16 hi = (_Float16)w;
    const size_t o = ((size_t)L * 256 + n) * 1792 + (size_t)g * 256 + k;
    wthi[o] = hi;
    wtlo[o] = (_Float16)(w - (float)hi);
}

// generic 256x256 [k][n] -> split planes [n][k]
__global__ __launch_bounds__(256) void wsplit_tr_kernel(const float* __restrict__ W,
                                                        _Float16* __restrict__ whi,
                                                        _Float16* __restrict__ wlo) {
    const int id = blockIdx.x * 256 + threadIdx.x;  // 65536
    const int k = id & 255, n = id >> 8;
    const float w = W[(size_t)k * 256 + n];
    const _Float16 hi = (_Float16)w;
    whi[(size_t)n * 256 + k] = hi;
    wlo[(size_t)n * 256 + k] = (_Float16)(w - (float)hi);
}

// ======= LDS-staged MFMA GEMM (m97 pattern): 128x128 tile, BK=32 ===========
// 4 waves (2m x 2n of 64x64). LDS: 4 planes x 512 units of 16B (32 KB).
// Unit (row, slot) at plane + (row*4+slot)*16B; slot holds global k-chunk
// c = slot ^ ((row>>1)&3)  (XOR swizzle, same on stage & read).
// A = [agg planes (K_agg, plane stride N_NODES*256) | h segment]; B [n][ldb].
// MODE 0: Cf = acc + bias
// MODE 1: v = acc + Cf; prelu -> Ohi/Olo planes; ss4[row*4+slot] = partial ss
// MODE 2: relu(acc + bias) -> Ohi/Olo planes
// MODE 3: Cf += acc
template <int MODE>
__global__ __launch_bounds__(256, 2) void gemm_lds(
    const _Float16* __restrict__ Ahi, const _Float16* __restrict__ Alo,
    const _Float16* __restrict__ Hhi, const _Float16* __restrict__ Hlo,
    const _Float16* __restrict__ Bhi, const _Float16* __restrict__ Blo,
    int ldb, int boff_agg, int boff_h, int K_agg, int K_tot,
    float* __restrict__ Cf, _Float16* __restrict__ Ohi, _Float16* __restrict__ Olo,
    const float* __restrict__ bias, const float* __restrict__ pa,
    float* __restrict__ ss4, int M) {
    __shared__ _Float16 smem[16384];  // 32 KB: Ah(4096) Al Bh Bl
    const int lane = threadIdx.x & 63;
    const int wave = threadIdx.x >> 6;
    const int lm = lane & 15, lq = lane >> 4;
    const int wm = wave & 1, wn = wave >> 1;
    const int mb = blockIdx.x * 128;
    const int nb = blockIdx.y * 128;

    // staging geometry: instr q of this wave covers units (q*4+wave)*64 + lane
    int uoff[2], aoff[2], boff[2];  // LDS unit offset; per-lane row/chunk offsets
    int arowg[2], browg[2], achk[2];
#pragma unroll
    for (int q = 0; q < 2; ++q) {
        const int u    = (q * 4 + wave) * 64 + lane;
        const int row  = u >> 2;
        const int slot = u & 3;
        const int c    = slot ^ ((row >> 1) & 3);
        uoff[q] = (q * 4 + wave) * 64;         // wave-uniform unit base
        int rg = mb + row; if (rg >= M) rg = M - 1;
        arowg[q] = rg;
        browg[q] = nb + row;
        achk[q]  = c * 8;                       // halves offset within k-slice
        (void)aoff; (void)boff;
    }

    f4 acc[4][4];
#pragma unroll
    for (int i = 0; i < 4; ++i)
#pragma unroll
        for (int j = 0; j < 4; ++j) acc[i][j] = (f4){0.f, 0.f, 0.f, 0.f};

    for (int k0 = 0; k0 < K_tot; k0 += 32) {
        const _Float16 *pAh, *pAl;
        int acol, bcol;
        if (k0 < K_agg) {
            const size_t pb = (size_t)(k0 >> 8) * (size_t)N_NODES * DD;
            pAh = Ahi + pb; pAl = Alo + pb;
            acol = k0 & 255;
            bcol = boff_agg + k0;
        } else {
            pAh = Hhi; pAl = Hlo;
            acol = k0 - K_agg;
            bcol = boff_h + (k0 - K_agg);
        }

        __syncthreads();  // previous tile fully consumed
#pragma unroll
        for (int q = 0; q < 2; ++q) {
            const size_t ga = (size_t)arowg[q] * DD + acol + achk[q];
            const size_t gb = (size_t)browg[q] * ldb + bcol + achk[q];
            _Float16* lbase = smem + (size_t)uoff[q] * 8;
            load_lds16(pAh + ga, lbase);
            load_lds16(pAl + ga, lbase + 4096);
            load_lds16(Bhi + gb, lbase + 8192);
            load_lds16(Blo + gb, lbase + 12288);
        }
        __syncthreads();  // staging drained (barrier implies vmcnt(0))

        h8 ah[4], al[4], bh[4], bl[4];
#pragma unroll
        for (int i = 0; i < 4; ++i) {
            const int row  = wm * 64 + i * 16 + lm;
            const int slot = lq ^ ((row >> 1) & 3);
            const int o    = (row * 4 + slot) * 8;
            ah[i] = *(const h8*)(smem + o);
            al[i] = *(const h8*)(smem + 4096 + o);
        }
#pragma unroll
        for (int j = 0; j < 4; ++j) {
            const int n    = wn * 64 + j * 16 + lm;
            const int slot = lq ^ ((n >> 1) & 3);
            const int o    = (n * 4 + slot) * 8;
            bh[j] = *(const h8*)(smem + 8192 + o);
            bl[j] = *(const h8*)(smem + 12288 + o);
        }
#pragma unroll
        for (int i = 0; i < 4; ++i)
#pragma unroll
            for (int j = 0; j < 4; ++j) {
                acc[i][j] = __builtin_amdgcn_mfma_f32_16x16x32_f16(ah[i], bh[j], acc[i][j], 0, 0, 0);
                acc[i][j] = __builtin_amdgcn_mfma_f32_16x16x32_f16(ah[i], bl[j], acc[i][j], 0, 0, 0);
                acc[i][j] = __builtin_amdgcn_mfma_f32_16x16x32_f16(al[i], bh[j], acc[i][j], 0, 0, 0);
            }
    }

    if (MODE == 0) {
#pragma unroll
        for (int i = 0; i < 4; ++i)
#pragma unroll
            for (int r = 0; r < 4; ++r) {
                const int row = mb + wm * 64 + i * 16 + lq * 4 + r;
                if (row >= M) continue;
#pragma unroll
                for (int j = 0; j < 4; ++j) {
                    const int col = nb + wn * 64 + j * 16 + lm;
                    Cf[(size_t)row * DD + col] = acc[i][j][r] + bias[col];
                }
            }
    } else if (MODE == 3) {
#pragma unroll
        for (int i = 0; i < 4; ++i)
#pragma unroll
            for (int r = 0; r < 4; ++r) {
                const int row = mb + wm * 64 + i * 16 + lq * 4 + r;
                if (row >= M) continue;
#pragma unroll
                for (int j = 0; j < 4; ++j) {
                    const int col = nb + wn * 64 + j * 16 + lm;
                    Cf[(size_t)row * DD + col] += acc[i][j][r];
                }
            }
    } else if (MODE == 2) {
#pragma unroll
        for (int i = 0; i < 4; ++i)
#pragma unroll
            for (int r = 0; r < 4; ++r) {
                const int row = mb + wm * 64 + i * 16 + lq * 4 + r;
                if (row >= M) continue;
#pragma unroll
                for (int j = 0; j < 4; ++j) {
                    const int col = nb + wn * 64 + j * 16 + lm;
                    const float v = fmaxf(acc[i][j][r] + bias[col], 0.f);
                    const _Float16 hi = (_Float16)v;
                    const size_t idx = (size_t)row * DD + col;
                    Ohi[idx] = hi;
                    Olo[idx] = (_Float16)(v - (float)hi);
                }
            }
    } else {  // MODE 1: add Cf, PReLU, write planes + ss partials
        const float a = pa[0];
#pragma unroll
        for (int i = 0; i < 4; ++i)
#pragma unroll
            for (int r = 0; r < 4; ++r) {
                const int row = mb + wm * 64 + i * 16 + lq * 4 + r;
                float rss = 0.f;
                if (row < M) {
#pragma unroll
                    for (int j = 0; j < 4; ++j) {
                        const int col = nb + wn * 64 + j * 16 + lm;
                        float v = acc[i][j][r] + Cf[(size_t)row * DD + col];
                        v = v > 0.f ? v : a * v;
                        const _Float16 hi = (_Float16)v;
                        const size_t idx = (size_t)row * DD + col;
                        Ohi[idx] = hi;
                        Olo[idx] = (_Float16)(v - (float)hi);
                        rss = fmaf(v, v, rss);
                    }
                }
                rss += __shfl_xor(rss, 1, 64);
                rss += __shfl_xor(rss, 2, 64);
                rss += __shfl_xor(rss, 4, 64);
                rss += __shfl_xor(rss, 8, 64);
                if (lm == 0 && row < M)
                    ss4[(size_t)row * 4 + blockIdx.y * 2 + wn] = rss;
            }
    }
}

// ---- normalize: h = (hi+lo) * rsqrt(sum ss partials), re-split planes ------
__global__ __launch_bounds__(256) void norm_kernel(_Float16* __restrict__ Hhi,
                                                   _Float16* __restrict__ Hlo,
                                                   const float* __restrict__ ss4) {
    const int node = blockIdx.x * 4 + (threadIdx.x >> 6);
    const int lane = threadIdx.x & 63;
    if (node >= N_NODES) return;
    const float tot = ss4[node * 4 + 0] + ss4[node * 4 + 1] +
                      ss4[node * 4 + 2] + ss4[node * 4 + 3];
    const float inv = 1.0f / fmaxf(sqrtf(tot), 1e-12f);
    const size_t o = (size_t)node * DD + lane * 4;
    h4 vh = *(const h4*)(Hhi + o);
    h4 vl = *(const h4*)(Hlo + o);
    h4 oh, ol;
#pragma unroll
    for (int e = 0; e < 4; ++e) {
        const float v = ((float)vh[e] + (float)vl[e]) * inv;
        oh[e] = (_Float16)v;
        ol[e] = (_Float16)(v - (float)oh[e]);
    }
    *(h4*)(Hhi + o) = oh;
    *(h4*)(Hlo + o) = ol;
}

// ================= CSR build: counting sort by key = rel*N_NODES + dst ======
__global__ __launch_bounds__(256) void hist_kernel(const int* __restrict__ dst,
                                                   const int* __restrict__ etype,
                                                   int* __restrict__ cnt) {
    const int e = blockIdx.x * 256 + threadIdx.x;
    if (e >= N_EDGES) return;
    atomicAdd(&cnt[etype[e] * N_NODES + dst[e]], 1);
}

__global__ __launch_bounds__(SCAN_T) void scan1_kernel(const int* __restrict__ cnt,
                                                       int* __restrict__ off,
                                                       int* __restrict__ bsum) {
    __shared__ int sh[SCAN_T];
    const int b = blockIdx.x, t = threadIdx.x;
    const int base = b * SCAN_CHUNK + t * SCAN_E;
    int pre[SCAN_E];
    int s = 0;
#pragma unroll
    for (int i = 0; i < SCAN_E; ++i) {
        const int x = (base + i < NKEYS) ? cnt[base + i] : 0;
        pre[i] = s;
        s += x;
    }
    sh[t] = s;
    __syncthreads();
    for (int d = 1; d < SCAN_T; d <<= 1) {
        const int x = (t >= d) ? sh[t - d] : 0;
        __syncthreads();
        sh[t] += x;
        __syncthreads();
    }
    const int toff = (t == 0) ? 0 : sh[t - 1];
#pragma unroll
    for (int i = 0; i < SCAN_E; ++i)
        if (base + i < NKEYS) off[base + i] = toff + pre[i];
    if (t == SCAN_T - 1) bsum[b] = sh[SCAN_T - 1];
}

__global__ __launch_bounds__(SCAN_T) void scan2_kernel(int* __restrict__ bsum, int n) {
    __shared__ int sh[SCAN_T];
    const int t = threadIdx.x;
    const int base = t * SCAN_E;
    int pre[SCAN_E];
    int s = 0;
#pragma unroll
    for (int i = 0; i < SCAN_E; ++i) {
        const int x = (base + i < n) ? bsum[base + i] : 0;
        pre[i] = s;
        s += x;
    }
    sh[t] = s;
    __syncthreads();
    for (int d = 1; d < SCAN_T; d <<= 1) {
        const int x = (t >= d) ? sh[t - d] : 0;
        __syncthreads();
        sh[t] += x;
        __syncthreads();
    }
    const int toff = (t == 0) ? 0 : sh[t - 1];
#pragma unroll
    for (int i = 0; i < SCAN_E; ++i)
        if (base + i < n) bsum[base + i] = toff + pre[i];
}

__global__ __launch_bounds__(SCAN_T) void scan3_kernel(int* __restrict__ off,
                                                       const int* __restrict__ bsum) {
    const int b = blockIdx.x, t = threadIdx.x;
    const int add = bsum[b];
    const int base = b * SCAN_CHUNK + t * SCAN_E;
#pragma unroll
    for (int i = 0; i < SCAN_E; ++i)
        if (base + i < NKEYS) off[base + i] += add;
    if (b == 0 && t == 0) off[NKEYS] = N_EDGES;
}

__global__ __launch_bounds__(256) void csr_fill_kernel(const int* __restrict__ src,
                                                       const int* __restrict__ dst,
                                                       const int* __restrict__ etype,
                                                       int* __restrict__ cursor,
                                                       int* __restrict__ sorted_src) {
    const int e = blockIdx.x * 256 + threadIdx.x;
    if (e >= N_EDGES) return;
    const int key = etype[e] * N_NODES + dst[e];
    const int pos = atomicAdd(&cursor[key], 1);
    sorted_src[pos] = src[e];
}

// ---------- aggregation of h (hi+lo planes) for 2 relations -> agg planes ---
__global__ __launch_bounds__(256) void agg2_kernel(const _Float16* __restrict__ Hhi,
                                                   const _Float16* __restrict__ Hlo,
                                                   const int* __restrict__ off,
                                                   const int* __restrict__ isrc,
                                                   _Float16* __restrict__ agghi,
                                                   _Float16* __restrict__ agglo, int rel0) {
    const int node = blockIdx.x * 4 + (threadIdx.x >> 6);
    const int lane = threadIdx.x & 63;
    if (node >= N_NODES) return;
#pragma unroll
    for (int rl = 0; rl < 2; ++rl) {
        const int r = rel0 + rl;
        const int s0 = off[r * N_NODES + node];
        const int s1 = off[r * N_NODES + node + 1];
        float a0 = 0.f, a1 = 0.f, a2 = 0.f, a3 = 0.f;
        for (int e = s0; e < s1; ++e) {
            const int s = isrc[e];
            const h4 vh = *(const h4*)(Hhi + (size_t)s * DD + lane * 4);
            const h4 vl = *(const h4*)(Hlo + (size_t)s * DD + lane * 4);
            a0 += (float)vh[0] + (float)vl[0];
            a1 += (float)vh[1] + (float)vl[1];
            a2 += (float)vh[2] + (float)vl[2];
            a3 += (float)vh[3] + (float)vl[3];
        }
        h4 oh, ol;
        oh[0] = (_Float16)a0; ol[0] = (_Float16)(a0 - (float)oh[0]);
        oh[1] = (_Float16)a1; ol[1] = (_Float16)(a1 - (float)oh[1]);
        oh[2] = (_Float16)a2; ol[2] = (_Float16)(a2 - (float)oh[2]);
        oh[3] = (_Float16)a3; ol[3] = (_Float16)(a3 - (float)oh[3]);
        const size_t o = ((size_t)rl * N_NODES + node) * DD + lane * 4;
        *(h4*)(agghi + o) = oh;
        *(h4*)(agglo + o) = ol;
    }
}

// ---------------- fp32 tiled GEMM for small fc tail (relu epilogue) ---------
__global__ __launch_bounds__(256) void gemm128x64(const float* __restrict__ A,
                                                  const float* __restrict__ B,
                                                  float* __restrict__ C,
                                                  const float* __restrict__ bias,
                                                  int M, int N, int K) {
    __shared__ float As[16 * 132];
    __shared__ float Bs[16 * 68];
    const int t  = threadIdx.x;
    const int tx = t & 15;
    const int ty = t >> 4;
    const int m0 = blockIdx.x * 128;
    const int n0 = blockIdx.y * 64;
    const int arow = t >> 2;
    const int ak   = (t & 3) * 4;
    const int bk   = t >> 4;
    const int bc   = (t & 15) * 4;

    float acc[8][4];
#pragma unroll
    for (int i = 0; i < 8; ++i)
#pragma unroll
        for (int j = 0; j < 4; ++j) acc[i][j] = 0.f;

    for (int k0 = 0; k0 < K; k0 += 16) {
        float4 a0 = {0.f, 0.f, 0.f, 0.f}, a1 = {0.f, 0.f, 0.f, 0.f};
        const int r0 = m0 + arow, r1 = r0 + 64;
        if (r0 < M) a0 = *reinterpret_cast<const float4*>(A + (size_t)r0 * K + k0 + ak);
        if (r1 < M) a1 = *reinterpret_cast<const float4*>(A + (size_t)r1 * K + k0 + ak);
        const float4 bb = *reinterpret_cast<const float4*>(B + (size_t)(k0 + bk) * N + n0 + bc);
        __syncthreads();
        As[(ak + 0) * 132 + arow] = a0.x;
        As[(ak + 1) * 132 + arow] = a0.y;
        As[(ak + 2) * 132 + arow] = a0.z;
        As[(ak + 3) * 132 + arow] = a0.w;
        As[(ak + 0) * 132 + arow + 64] = a1.x;
        As[(ak + 1) * 132 + arow + 64] = a1.y;
        As[(ak + 2) * 132 + arow + 64] = a1.z;
        As[(ak + 3) * 132 + arow + 64] = a1.w;
        *reinterpret_cast<float4*>(&Bs[bk * 68 + bc]) = bb;
        __syncthreads();
#pragma unroll
        for (int k = 0; k < 16; ++k) {
            const float4 fa0 = *reinterpret_cast<const float4*>(&As[k * 132 + ty * 8]);
            const float4 fa1 = *reinterpret_cast<const float4*>(&As[k * 132 + ty * 8 + 4]);
            const float4 fb  = *reinterpret_cast<const float4*>(&Bs[k * 68 + tx * 4]);
            const float av[8] = {fa0.x, fa0.y, fa0.z, fa0.w, fa1.x, fa1.y, fa1.z, fa1.w};
            const float bv[4] = {fb.x, fb.y, fb.z, fb.w};
#pragma unroll
            for (int i = 0; i < 8; ++i)
#pragma unroll
                for (int j = 0; j < 4; ++j) acc[i][j] = fmaf(av[i], bv[j], acc[i][j]);
        }
    }
    const int row = m0 + ty * 8;
    const int col = n0 + tx * 4;
    const float4 bv = *reinterpret_cast<const float4*>(bias + col);
#pragma unroll
    for (int i = 0; i < 8; ++i) {
        const int m = row + i;
        if (m >= M) continue;
        float4 v = {acc[i][0], acc[i][1], acc[i][2], acc[i][3]};
        v.x = fmaxf(v.x + bv.x, 0.f); v.y = fmaxf(v.y + bv.y, 0.f);
        v.z = fmaxf(v.z + bv.z, 0.f); v.w = fmaxf(v.w + bv.w, 0.f);
        *reinterpret_cast<float4*>(C + (size_t)m * N + col) = v;
    }
}

// ---------------- pooled[batch[n]] += g[n]  (batch sorted) ------------------
__global__ __launch_bounds__(64) void pool_kernel(const float* __restrict__ g,
                                                  const int* __restrict__ batch,
                                                  float* __restrict__ pooled) {
    const int c     = threadIdx.x;
    const int start = blockIdx.x * 128;
    const int end   = min(start + 128, N_NODES);
    int cur = batch[start];
    float4 acc = {0.f, 0.f, 0.f, 0.f};
    for (int n = start; n < end; ++n) {
        const int bn = batch[n];
        if (bn != cur) {
            float* p = pooled + (size_t)cur * DD + c * 4;
            atomAddF(p + 0, acc.x); atomAddF(p + 1, acc.y);
            atomAddF(p + 2, acc.z); atomAddF(p + 3, acc.w);
            acc = {0.f, 0.f, 0.f, 0.f};
            cur = bn;
        }
        const float4 v = reinterpret_cast<const float4*>(g + (size_t)n * DD)[c];
        acc.x += v.x; acc.y += v.y; acc.z += v.z; acc.w += v.w;
    }
    float* p = pooled + (size_t)cur * DD + c * 4;
    atomAddF(p + 0, acc.x); atomAddF(p + 1, acc.y);
    atomAddF(p + 2, acc.z); atomAddF(p + 3, acc.w);
}

__global__ __launch_bounds__(64) void out_kernel(const float* __restrict__ z2,
                                                 const float* __restrict__ W,
                                                 const float* __restrict__ b,
                                                 float* __restrict__ out) {
    const int g = blockIdx.x;
    const int t = threadIdx.x;
    float s = 0.f;
#pragma unroll
    for (int j = 0; j < 8; ++j) s = fmaf(z2[(size_t)g * 512 + t + 64 * j], W[t + 64 * j], s);
#pragma unroll
    for (int off = 32; off; off >>= 1) s += __shfl_xor(s, off, 64);
    if (t == 0) {
        const float v = s + b[0];
        out[g] = v > 0.f ? v : 0.f;
    }
}

extern "C" void kernel_launch(void* const* d_in, const int* in_sizes, int n_in,
                              void* d_out, int out_size, void* d_ws, size_t ws_size,
                              hipStream_t stream) {
    const float* x       = (const float*)d_in[0];
    const int*   eidx    = (const int*)d_in[1];
    const int*   etype   = (const int*)d_in[2];
    const int*   batch   = (const int*)d_in[3];
    const float* enc_W   = (const float*)d_in[4];
    const float* enc_b   = (const float*)d_in[5];
    const float* prelu_a = (const float*)d_in[6];
    const float* rel_W   = (const float*)d_in[7];
    const float* root_W  = (const float*)d_in[8];
    const float* conv_b  = (const float*)d_in[9];
    const float* gp_W1   = (const float*)d_in[10];
    const float* gp_b1   = (const float*)d_in[11];
    const float* gp_W2   = (const float*)d_in[12];
    const float* gp_b2   = (const float*)d_in[13];
    const float* fc_W1   = (const float*)d_in[14];
    const float* fc_b1   = (const float*)d_in[15];
    const float* fc_W2   = (const float*)d_in[16];
    const float* fc_b2   = (const float*)d_in[17];
    const float* out_W   = (const float*)d_in[18];
    const float* out_b   = (const float*)d_in[19];
    float* out = (float*)d_out;

    // workspace arena — keep total < ~256 MiB (277 MB crashed; 229 MB runs)
    uint8_t* wp = (uint8_t*)d_ws;
    auto alloc = [&](size_t bytes) {
        void* r = (void*)wp;
        wp += (bytes + 255) & ~(size_t)255;
        return r;
    };
    float*    base   = (float*)alloc((size_t)N_NODES * DD * 4);          // 51.2 MB
    _Float16* Hhi    = (_Float16*)alloc((size_t)N_NODES * DD * 2);       // 25.6 MB
    _Float16* Hlo    = (_Float16*)alloc((size_t)N_NODES * DD * 2);       // 25.6 MB
    _Float16* agghi  = (_Float16*)alloc((size_t)2 * N_NODES * DD * 2);   // 51.2 MB
    _Float16* agglo  = (_Float16*)alloc((size_t)2 * N_NODES * DD * 2);   // 51.2 MB
    _Float16* wthi   = (_Float16*)alloc((size_t)N_LAYERS * 256 * 1792 * 2);
    _Float16* wtlo   = (_Float16*)alloc((size_t)N_LAYERS * 256 * 1792 * 2);
    _Float16* wtg1hi = (_Float16*)alloc((size_t)256 * 256 * 2);
    _Float16* wtg1lo = (_Float16*)alloc((size_t)256 * 256 * 2);
    _Float16* wtg2hi = (_Float16*)alloc((size_t)256 * 256 * 2);
    _Float16* wtg2lo = (_Float16*)alloc((size_t)256 * 256 * 2);
    float*    ss4    = (float*)alloc((size_t)N_NODES * 4 * 4);           // 0.8 MB
    float*    pooled = (float*)alloc((size_t)NUM_GRAPHS * DD * 4);
    float*    z1     = (float*)alloc((size_t)NUM_GRAPHS * 1024 * 4);
    float*    z2     = (float*)alloc((size_t)NUM_GRAPHS * 512 * 4);
    int*      ioff   = (int*)alloc((size_t)(NKEYS + 1) * 4);
    int*      icur   = (int*)alloc((size_t)NKEYS * 4);
    int*      ibsum  = (int*)alloc(256 * 4);
    int*      isrc   = (int*)alloc((size_t)N_EDGES * 4);
    // total ≈ 230 MB

    const int* src = eidx;
    const int* dst = eidx + N_EDGES;

    // ---- weight prep ----
    const size_t wtot = (size_t)N_LAYERS * 7 * 256 * 256;
    wsplit_rel_kernel<<<(int)((wtot + 255) / 256), 256, 0, stream>>>(rel_W, root_W, wthi, wtlo);
    wsplit_tr_kernel<<<256, 256, 0, stream>>>(gp_W1, wtg1hi, wtg1lo);
    wsplit_tr_kernel<<<256, 256, 0, stream>>>(gp_W2, wtg2hi, wtg2lo);

    // ---- CSR build ----
    hipMemsetAsync(icur, 0, (size_t)NKEYS * sizeof(int), stream);
    const int eb = (N_EDGES + 255) / 256;
    hist_kernel<<<eb, 256, 0, stream>>>(dst, etype, icur);
    scan1_kernel<<<SCAN_NB, SCAN_T, 0, stream>>>(icur, ioff, ibsum);
    scan2_kernel<<<1, SCAN_T, 0, stream>>>(ibsum, SCAN_NB);
    scan3_kernel<<<SCAN_NB, SCAN_T, 0, stream>>>(ioff, ibsum);
    hipMemcpyAsync(icur, ioff, (size_t)NKEYS * sizeof(int), hipMemcpyDeviceToDevice, stream);
    csr_fill_kernel<<<eb, 256, 0, stream>>>(src, dst, etype, icur, isrc);

    // ---- encoder ----
    enc_kernel<<<N_NODES, 256, 0, stream>>>(x, enc_W, enc_b, Hhi, Hlo);

    const dim3 gG((N_NODES + 127) / 128, 2);  // 391 x 2
    const int  nodeb = (N_NODES + 3) / 4;

    for (int L = 0; L < N_LAYERS; ++L) {
        const _Float16* Bh = wthi + (size_t)L * 256 * 1792;
        const _Float16* Bl = wtlo + (size_t)L * 256 * 1792;
        // chunk 1: rels 0,1 (K_agg=512) + root+I via h segment (K=256) + conv_b
        agg2_kernel<<<nodeb, 256, 0, stream>>>(Hhi, Hlo, ioff, isrc, agghi, agglo, 0);
        gemm_lds<0><<<gG, 256, 0, stream>>>(agghi, agglo, Hhi, Hlo, Bh, Bl,
                                            1792, 0, 1536, 512, 768,
                                            base, nullptr, nullptr,
                                            conv_b + L * DD, nullptr, nullptr, N_NODES);
        // chunk 2: rels 2,3 accumulate into base
        agg2_kernel<<<nodeb, 256, 0, stream>>>(Hhi, Hlo, ioff, isrc, agghi, agglo, 2);
        gemm_lds<3><<<gG, 256, 0, stream>>>(agghi, agglo, Hhi, Hlo, Bh, Bl,
                                            1792, 512, 0, 512, 512,
                                            base, nullptr, nullptr,
                                            nullptr, nullptr, nullptr, N_NODES);
        // chunk 3: rels 4,5 + add base + PReLU -> planes, ss partials
        agg2_kernel<<<nodeb, 256, 0, stream>>>(Hhi, Hlo, ioff, isrc, agghi, agglo, 4);
        gemm_lds<1><<<gG, 256, 0, stream>>>(agghi, agglo, Hhi, Hlo, Bh, Bl,
                                            1792, 1024, 0, 512, 512,
                                            base, Hhi, Hlo,
                                            nullptr, prelu_a, ss4, N_NODES);
        // L2-normalize planes
        norm_kernel<<<nodeb, 256, 0, stream>>>(Hhi, Hlo, ss4);
    }

    // gp1 = relu(h @ gp_W1 + gp_b1) -> planes (reuse agg buffers)
    gemm_lds<2><<<gG, 256, 0, stream>>>(nullptr, nullptr, Hhi, Hlo, wtg1hi, wtg1lo,
                                        256, 0, 0, 0, 256,
                                        nullptr, agghi, agglo, gp_b1, nullptr, nullptr, N_NODES);
    // gp2 = gp1 @ gp_W2 + gp_b2 -> base (fp32)
    gemm_lds<0><<<gG, 256, 0, stream>>>(agghi, agglo, nullptr, nullptr, wtg2hi, wtg2lo,
                                        256, 0, 0, 256, 256,
                                        base, nullptr, nullptr, gp_b2, nullptr, nullptr, N_NODES);

    hipMemsetAsync(pooled, 0, (size_t)NUM_GRAPHS * DD * sizeof(float), stream);
    pool_kernel<<<(N_NODES + 127) / 128, 64, 0, stream>>>(base, batch, pooled);

    gemm128x64<<<dim3(4, 16), 256, 0, stream>>>(pooled, fc_W1, z1, fc_b1,
                                                NUM_GRAPHS, 1024, DD);
    gemm128x64<<<dim3(4, 8), 256, 0, stream>>>(z1, fc_W2, z2, fc_b2,
                                               NUM_GRAPHS, 512, 1024);
    out_kernel<<<NUM_GRAPHS, 64, 0, stream>>>(z2, out_W, out_b, out);
}

// Round 7
// 3632.846 us; speedup vs baseline: 1.5661x; 1.0190x over previous
//
#include <hip/hip_runtime.h>

#define N_NODES   50000
#define N_EDGES   800000
#define N_REL     6
#define N_LAYERS  8
#define DD        256
#define NUM_GRAPHS 512

#define NKEYS      (N_REL * N_NODES)
#define SCAN_T     256
#define SCAN_E     8
#define SCAN_CHUNK (SCAN_T * SCAN_E)
#define SCAN_NB    ((NKEYS + SCAN_CHUNK - 1) / SCAN_CHUNK)

typedef _Float16 h4 __attribute__((ext_vector_type(4)));
typedef _Float16 h8 __attribute__((ext_vector_type(8)));
typedef float    f4 __attribute__((ext_vector_type(4)));

__device__ __forceinline__ void atomAddF(float* p, float v) { unsafeAtomicAdd(p, v); }

// async global->LDS, 16B per lane. LDS ptr must be wave-uniform; global per-lane.
__device__ __forceinline__ void load_lds16(const void* g, void* l) {
    __builtin_amdgcn_global_load_lds(
        (const __attribute__((address_space(1))) uint32_t*)g,
        (__attribute__((address_space(3))) uint32_t*)l, 16, 0, 0);
}

// ---------------- encoder: h = x @ enc_W + enc_b, write hi/lo fp16 planes ---
__global__ __launch_bounds__(256) void enc_kernel(const float* __restrict__ x,
                                                  const float* __restrict__ W,
                                                  const float* __restrict__ b,
                                                  _Float16* __restrict__ Hhi,
                                                  _Float16* __restrict__ Hlo) {
    int n = blockIdx.x;
    int d = threadIdx.x;
    float s = b[d];
#pragma unroll
    for (int k = 0; k < 13; ++k) s = fmaf(x[n * 13 + k], W[k * 256 + d], s);
    const _Float16 hi = (_Float16)s;
    Hhi[(size_t)n * DD + d] = hi;
    Hlo[(size_t)n * DD + d] = (_Float16)(s - (float)hi);
}

// ------------- weight split+transpose: rel_W/root_W(+I) -> WT[L][n][1792] ---
__global__ __launch_bounds__(256) void wsplit_rel_kernel(const float* __restrict__ relW,
                                                         const float* __restrict__ rootW,
                                                         _Float16* __restrict__ wthi,
                                                         _Float16* __restrict__ wtlo) {
    const size_t id = (size_t)blockIdx.x * 256 + threadIdx.x;
    if (id >= (size_t)N_LAYERS * 7 * 256 * 256) return;
    const int k = (int)(id & 255);
    const int n = (int)((id >> 8) & 255);
    const int g = (int)((id >> 16) % 7);
    const int L = (int)((id >> 16) / 7);
    float w = (g < 6)
        ? relW[(((size_t)L * 6 + g) * 256 + k) * 256 + n]
        : rootW[((size_t)L * 256 + k) * 256 + n];
    if (g == 6 && k == n) w += 1.0f;  // fold skip: h@(root+I) = h@root + h
    const _Float16 hi = (_Float16)w;
    const size_t o = ((size_t)L * 256 + n) * 1792 + (size_t)g * 256 + k;
    wthi[o] = hi;
    wtlo[o] = (_Float16)(w - (float)hi);
}

// generic [K][N] -> split planes [N][K]
__global__ __launch_bounds__(256) void wsplit_tr_kernel(const float* __restrict__ W,
                                                        _Float16* __restrict__ whi,
                                                        _Float16* __restrict__ wlo,
                                                        int K, int N) {
    const size_t id = (size_t)blockIdx.x * 256 + threadIdx.x;
    if (id >= (size_t)K * N) return;
    const int k = (int)(id % K), n = (int)(id / K);
    const float w = W[(size_t)k * N + n];
    const _Float16 hi = (_Float16)w;
    whi[(size_t)n * K + k] = hi;
    wlo[(size_t)n * K + k] = (_Float16)(w - (float)hi);
}

// split fp32 [M][N] -> hi/lo planes
__global__ __launch_bounds__(256) void fsplit_kernel(const float* __restrict__ S,
                                                     _Float16* __restrict__ hi,
                                                     _Float16* __restrict__ lo, int total) {
    const int id = blockIdx.x * 256 + threadIdx.x;
    if (id >= total) return;
    const float v = S[id];
    const _Float16 h = (_Float16)v;
    hi[id] = h;
    lo[id] = (_Float16)(v - (float)h);
}

// ======= LDS-staged MFMA GEMM (m97 pattern): 128x128 tile, BK=32 ===========
// 4 waves (2m x 2n of 64x64). LDS: 4 planes x 512 units of 16B (32 KB).
// Unit (row, slot) at plane + (row*4+slot)*16B; slot holds global k-chunk
// c = slot ^ ((row>>1)&3)  (XOR swizzle, same on stage & read).
// A = [agg planes (K_agg, plane stride N_NODES*DD, row stride lda) | h seg];
// B planes [n][ldb]; C row stride ldc; grid.y covers N/128 tiles.
// MODE 0: Cf = acc + bias
// MODE 1: v = acc + Cf; prelu -> Ohi/Olo planes; ss4 partials (grid.y==2 only)
// MODE 2: relu(acc + bias) -> Ohi/Olo planes
// MODE 3: Cf += acc
template <int MODE>
__global__ __launch_bounds__(256, 2) void gemm_lds(
    const _Float16* __restrict__ Ahi, const _Float16* __restrict__ Alo,
    const _Float16* __restrict__ Hhi, const _Float16* __restrict__ Hlo,
    const _Float16* __restrict__ Bhi, const _Float16* __restrict__ Blo,
    int lda, int ldb, int ldc, int boff_agg, int boff_h, int K_agg, int K_tot,
    float* __restrict__ Cf, _Float16* __restrict__ Ohi, _Float16* __restrict__ Olo,
    const float* __restrict__ bias, const float* __restrict__ pa,
    float* __restrict__ ss4, int M) {
    __shared__ _Float16 smem[16384];  // 32 KB: Ah(4096) Al Bh Bl
    const int lane = threadIdx.x & 63;
    const int wave = threadIdx.x >> 6;
    const int lm = lane & 15, lq = lane >> 4;
    const int wm = wave & 1, wn = wave >> 1;
    const int mb = blockIdx.x * 128;
    const int nb = blockIdx.y * 128;

    int uoff[2], arowg[2], browg[2], achk[2];
#pragma unroll
    for (int q = 0; q < 2; ++q) {
        const int u    = (q * 4 + wave) * 64 + lane;
        const int row  = u >> 2;
        const int slot = u & 3;
        const int c    = slot ^ ((row >> 1) & 3);
        uoff[q] = (q * 4 + wave) * 64;
        int rg = mb + row; if (rg >= M) rg = M - 1;
        arowg[q] = rg;
        browg[q] = nb + row;
        achk[q]  = c * 8;
    }

    f4 acc[4][4];
#pragma unroll
    for (int i = 0; i < 4; ++i)
#pragma unroll
        for (int j = 0; j < 4; ++j) acc[i][j] = (f4){0.f, 0.f, 0.f, 0.f};

    for (int k0 = 0; k0 < K_tot; k0 += 32) {
        const _Float16 *pAh, *pAl;
        int acol, bcol;
        if (k0 < K_agg) {
            const size_t pb = (size_t)(k0 >> 8) * (size_t)N_NODES * DD;
            pAh = Ahi + pb; pAl = Alo + pb;
            acol = k0 & 255;
            bcol = boff_agg + k0;
        } else {
            pAh = Hhi; pAl = Hlo;
            acol = k0 - K_agg;
            bcol = boff_h + (k0 - K_agg);
        }

        __syncthreads();  // previous tile fully consumed
#pragma unroll
        for (int q = 0; q < 2; ++q) {
            const size_t ga = (size_t)arowg[q] * lda + acol + achk[q];
            const size_t gb = (size_t)browg[q] * ldb + bcol + achk[q];
            _Float16* lbase = smem + (size_t)uoff[q] * 8;
            load_lds16(pAh + ga, lbase);
            load_lds16(pAl + ga, lbase + 4096);
            load_lds16(Bhi + gb, lbase + 8192);
            load_lds16(Blo + gb, lbase + 12288);
        }
        __syncthreads();  // staging drained

        h8 ah[4], al[4], bh[4], bl[4];
#pragma unroll
        for (int i = 0; i < 4; ++i) {
            const int row  = wm * 64 + i * 16 + lm;
            const int slot = lq ^ ((row >> 1) & 3);
            const int o    = (row * 4 + slot) * 8;
            ah[i] = *(const h8*)(smem + o);
            al[i] = *(const h8*)(smem + 4096 + o);
        }
#pragma unroll
        for (int j = 0; j < 4; ++j) {
            const int n    = wn * 64 + j * 16 + lm;
            const int slot = lq ^ ((n >> 1) & 3);
            const int o    = (n * 4 + slot) * 8;
            bh[j] = *(const h8*)(smem + 8192 + o);
            bl[j] = *(const h8*)(smem + 12288 + o);
        }
#pragma unroll
        for (int i = 0; i < 4; ++i)
#pragma unroll
            for (int j = 0; j < 4; ++j) {
                acc[i][j] = __builtin_amdgcn_mfma_f32_16x16x32_f16(ah[i], bh[j], acc[i][j], 0, 0, 0);
                acc[i][j] = __builtin_amdgcn_mfma_f32_16x16x32_f16(ah[i], bl[j], acc[i][j], 0, 0, 0);
                acc[i][j] = __builtin_amdgcn_mfma_f32_16x16x32_f16(al[i], bh[j], acc[i][j], 0, 0, 0);
            }
    }

    if (MODE == 0) {
#pragma unroll
        for (int i = 0; i < 4; ++i)
#pragma unroll
            for (int r = 0; r < 4; ++r) {
                const int row = mb + wm * 64 + i * 16 + lq * 4 + r;
                if (row >= M) continue;
#pragma unroll
                for (int j = 0; j < 4; ++j) {
                    const int col = nb + wn * 64 + j * 16 + lm;
                    Cf[(size_t)row * ldc + col] = acc[i][j][r] + bias[col];
                }
            }
    } else if (MODE == 3) {
#pragma unroll
        for (int i = 0; i < 4; ++i)
#pragma unroll
            for (int r = 0; r < 4; ++r) {
                const int row = mb + wm * 64 + i * 16 + lq * 4 + r;
                if (row >= M) continue;
#pragma unroll
                for (int j = 0; j < 4; ++j) {
                    const int col = nb + wn * 64 + j * 16 + lm;
                    Cf[(size_t)row * ldc + col] += acc[i][j][r];
                }
            }
    } else if (MODE == 2) {
#pragma unroll
        for (int i = 0; i < 4; ++i)
#pragma unroll
            for (int r = 0; r < 4; ++r) {
                const int row = mb + wm * 64 + i * 16 + lq * 4 + r;
                if (row >= M) continue;
#pragma unroll
                for (int j = 0; j < 4; ++j) {
                    const int col = nb + wn * 64 + j * 16 + lm;
                    const float v = fmaxf(acc[i][j][r] + bias[col], 0.f);
                    const _Float16 hi = (_Float16)v;
                    const size_t idx = (size_t)row * ldc + col;
                    Ohi[idx] = hi;
                    Olo[idx] = (_Float16)(v - (float)hi);
                }
            }
    } else {  // MODE 1: add Cf, PReLU, write planes + ss partials
        const float a = pa[0];
#pragma unroll
        for (int i = 0; i < 4; ++i)
#pragma unroll
            for (int r = 0; r < 4; ++r) {
                const int row = mb + wm * 64 + i * 16 + lq * 4 + r;
                float rss = 0.f;
                if (row < M) {
#pragma unroll
                    for (int j = 0; j < 4; ++j) {
                        const int col = nb + wn * 64 + j * 16 + lm;
                        float v = acc[i][j][r] + Cf[(size_t)row * ldc + col];
                        v = v > 0.f ? v : a * v;
                        const _Float16 hi = (_Float16)v;
                        const size_t idx = (size_t)row * ldc + col;
                        Ohi[idx] = hi;
                        Olo[idx] = (_Float16)(v - (float)hi);
                        rss = fmaf(v, v, rss);
                    }
                }
                rss += __shfl_xor(rss, 1, 64);
                rss += __shfl_xor(rss, 2, 64);
                rss += __shfl_xor(rss, 4, 64);
                rss += __shfl_xor(rss, 8, 64);
                if (lm == 0 && row < M)
                    ss4[(size_t)row * 4 + blockIdx.y * 2 + wn] = rss;
            }
    }
}

// ---- normalize: h = (hi+lo) * rsqrt(sum ss partials), re-split planes ------
__global__ __launch_bounds__(256) void norm_kernel(_Float16* __restrict__ Hhi,
                                                   _Float16* __restrict__ Hlo,
                                                   const float* __restrict__ ss4) {
    const int node = blockIdx.x * 4 + (threadIdx.x >> 6);
    const int lane = threadIdx.x & 63;
    if (node >= N_NODES) return;
    const float tot = ss4[node * 4 + 0] + ss4[node * 4 + 1] +
                      ss4[node * 4 + 2] + ss4[node * 4 + 3];
    const float inv = 1.0f / fmaxf(sqrtf(tot), 1e-12f);
    const size_t o = (size_t)node * DD + lane * 4;
    h4 vh = *(const h4*)(Hhi + o);
    h4 vl = *(const h4*)(Hlo + o);
    h4 oh, ol;
#pragma unroll
    for (int e = 0; e < 4; ++e) {
        const float v = ((float)vh[e] + (float)vl[e]) * inv;
        oh[e] = (_Float16)v;
        ol[e] = (_Float16)(v - (float)oh[e]);
    }
    *(h4*)(Hhi + o) = oh;
    *(h4*)(Hlo + o) = ol;
}

// ================= CSR build: counting sort by key = rel*N_NODES + dst ======
__global__ __launch_bounds__(256) void hist_kernel(const int* __restrict__ dst,
                                                   const int* __restrict__ etype,
                                                   int* __restrict__ cnt) {
    const int e = blockIdx.x * 256 + threadIdx.x;
    if (e >= N_EDGES) return;
    atomicAdd(&cnt[etype[e] * N_NODES + dst[e]], 1);
}

__global__ __launch_bounds__(SCAN_T) void scan1_kernel(const int* __restrict__ cnt,
                                                       int* __restrict__ off,
                                                       int* __restrict__ bsum) {
    __shared__ int sh[SCAN_T];
    const int b = blockIdx.x, t = threadIdx.x;
    const int base = b * SCAN_CHUNK + t * SCAN_E;
    int pre[SCAN_E];
    int s = 0;
#pragma unroll
    for (int i = 0; i < SCAN_E; ++i) {
        const int x = (base + i < NKEYS) ? cnt[base + i] : 0;
        pre[i] = s;
        s += x;
    }
    sh[t] = s;
    __syncthreads();
    for (int d = 1; d < SCAN_T; d <<= 1) {
        const int x = (t >= d) ? sh[t - d] : 0;
        __syncthreads();
        sh[t] += x;
        __syncthreads();
    }
    const int toff = (t == 0) ? 0 : sh[t - 1];
#pragma unroll
    for (int i = 0; i < SCAN_E; ++i)
        if (base + i < NKEYS) off[base + i] = toff + pre[i];
    if (t == SCAN_T - 1) bsum[b] = sh[SCAN_T - 1];
}

__global__ __launch_bounds__(SCAN_T) void scan2_kernel(int* __restrict__ bsum, int n) {
    __shared__ int sh[SCAN_T];
    const int t = threadIdx.x;
    const int base = t * SCAN_E;
    int pre[SCAN_E];
    int s = 0;
#pragma unroll
    for (int i = 0; i < SCAN_E; ++i) {
        const int x = (base + i < n) ? bsum[base + i] : 0;
        pre[i] = s;
        s += x;
    }
    sh[t] = s;
    __syncthreads();
    for (int d = 1; d < SCAN_T; d <<= 1) {
        const int x = (t >= d) ? sh[t - d] : 0;
        __syncthreads();
        sh[t] += x;
        __syncthreads();
    }
    const int toff = (t == 0) ? 0 : sh[t - 1];
#pragma unroll
    for (int i = 0; i < SCAN_E; ++i)
        if (base + i < n) bsum[base + i] = toff + pre[i];
}

__global__ __launch_bounds__(SCAN_T) void scan3_kernel(int* __restrict__ off,
                                                       const int* __restrict__ bsum) {
    const int b = blockIdx.x, t = threadIdx.x;
    const int add = bsum[b];
    const int base = b * SCAN_CHUNK + t * SCAN_E;
#pragma unroll
    for (int i = 0; i < SCAN_E; ++i)
        if (base + i < NKEYS) off[base + i] += add;
    if (b == 0 && t == 0) off[NKEYS] = N_EDGES;
}

__global__ __launch_bounds__(256) void csr_fill_kernel(const int* __restrict__ src,
                                                       const int* __restrict__ dst,
                                                       const int* __restrict__ etype,
                                                       int* __restrict__ cursor,
                                                       int* __restrict__ sorted_src) {
    const int e = blockIdx.x * 256 + threadIdx.x;
    if (e >= N_EDGES) return;
    const int key = etype[e] * N_NODES + dst[e];
    const int pos = atomicAdd(&cursor[key], 1);
    sorted_src[pos] = src[e];
}

// ---------- aggregation: one wave per (node, rel half) -> agg planes --------
__global__ __launch_bounds__(256) void agg2_kernel(const _Float16* __restrict__ Hhi,
                                                   const _Float16* __restrict__ Hlo,
                                                   const int* __restrict__ off,
                                                   const int* __restrict__ isrc,
                                                   _Float16* __restrict__ agghi,
                                                   _Float16* __restrict__ agglo, int rel0) {
    const int pair = blockIdx.x * 4 + (threadIdx.x >> 6);  // 0..2*N_NODES-1
    const int lane = threadIdx.x & 63;
    if (pair >= 2 * N_NODES) return;
    const int rl   = (pair >= N_NODES) ? 1 : 0;
    const int node = pair - rl * N_NODES;
    const int r    = rel0 + rl;
    const int s0 = off[r * N_NODES + node];
    const int s1 = off[r * N_NODES + node + 1];
    float a0 = 0.f, a1 = 0.f, a2 = 0.f, a3 = 0.f;
    for (int e = s0; e < s1; ++e) {
        const int s = isrc[e];
        const h4 vh = *(const h4*)(Hhi + (size_t)s * DD + lane * 4);
        const h4 vl = *(const h4*)(Hlo + (size_t)s * DD + lane * 4);
        a0 += (float)vh[0] + (float)vl[0];
        a1 += (float)vh[1] + (float)vl[1];
        a2 += (float)vh[2] + (float)vl[2];
        a3 += (float)vh[3] + (float)vl[3];
    }
    h4 oh, ol;
    oh[0] = (_Float16)a0; ol[0] = (_Float16)(a0 - (float)oh[0]);
    oh[1] = (_Float16)a1; ol[1] = (_Float16)(a1 - (float)oh[1]);
    oh[2] = (_Float16)a2; ol[2] = (_Float16)(a2 - (float)oh[2]);
    oh[3] = (_Float16)a3; ol[3] = (_Float16)(a3 - (float)oh[3]);
    const size_t o = ((size_t)rl * N_NODES + node) * DD + lane * 4;
    *(h4*)(agghi + o) = oh;
    *(h4*)(agglo + o) = ol;
}

// ---------------- pooled[batch[n]] += g[n]  (batch sorted) ------------------
__global__ __launch_bounds__(64) void pool_kernel(const float* __restrict__ g,
                                                  const int* __restrict__ batch,
                                                  float* __restrict__ pooled) {
    const int c     = threadIdx.x;
    const int start = blockIdx.x * 128;
    const int end   = min(start + 128, N_NODES);
    int cur = batch[start];
    float4 acc = {0.f, 0.f, 0.f, 0.f};
    for (int n = start; n < end; ++n) {
        const int bn = batch[n];
        if (bn != cur) {
            float* p = pooled + (size_t)cur * DD + c * 4;
            atomAddF(p + 0, acc.x); atomAddF(p + 1, acc.y);
            atomAddF(p + 2, acc.z); atomAddF(p + 3, acc.w);
            acc = {0.f, 0.f, 0.f, 0.f};
            cur = bn;
        }
        const float4 v = reinterpret_cast<const float4*>(g + (size_t)n * DD)[c];
        acc.x += v.x; acc.y += v.y; acc.z += v.z; acc.w += v.w;
    }
    float* p = pooled + (size_t)cur * DD + c * 4;
    atomAddF(p + 0, acc.x); atomAddF(p + 1, acc.y);
    atomAddF(p + 2, acc.z); atomAddF(p + 3, acc.w);
}

// ---------------- out = relu((z2hi+z2lo) @ out_W + out_b) -------------------
__global__ __launch_bounds__(64) void out_kernel(const _Float16* __restrict__ z2hi,
                                                 const _Float16* __restrict__ z2lo,
                                                 const float* __restrict__ W,
                                                 const float* __restrict__ b,
                                                 float* __restrict__ out) {
    const int g = blockIdx.x;
    const int t = threadIdx.x;
    float s = 0.f;
#pragma unroll
    for (int j = 0; j < 8; ++j) {
        const int idx = t + 64 * j;
        const float z = (float)z2hi[(size_t)g * 512 + idx] + (float)z2lo[(size_t)g * 512 + idx];
        s = fmaf(z, W[idx], s);
    }
#pragma unroll
    for (int off = 32; off; off >>= 1) s += __shfl_xor(s, off, 64);
    if (t == 0) {
        const float v = s + b[0];
        out[g] = v > 0.f ? v : 0.f;
    }
}

extern "C" void kernel_launch(void* const* d_in, const int* in_sizes, int n_in,
                              void* d_out, int out_size, void* d_ws, size_t ws_size,
                              hipStream_t stream) {
    const float* x       = (const float*)d_in[0];
    const int*   eidx    = (const int*)d_in[1];
    const int*   etype   = (const int*)d_in[2];
    const int*   batch   = (const int*)d_in[3];
    const float* enc_W   = (const float*)d_in[4];
    const float* enc_b   = (const float*)d_in[5];
    const float* prelu_a = (const float*)d_in[6];
    const float* rel_W   = (const float*)d_in[7];
    const float* root_W  = (const float*)d_in[8];
    const float* conv_b  = (const float*)d_in[9];
    const float* gp_W1   = (const float*)d_in[10];
    const float* gp_b1   = (const float*)d_in[11];
    const float* gp_W2   = (const float*)d_in[12];
    const float* gp_b2   = (const float*)d_in[13];
    const float* fc_W1   = (const float*)d_in[14];
    const float* fc_b1   = (const float*)d_in[15];
    const float* fc_W2   = (const float*)d_in[16];
    const float* fc_b2   = (const float*)d_in[17];
    const float* out_W   = (const float*)d_in[18];
    const float* out_b   = (const float*)d_in[19];
    float* out = (float*)d_out;

    // workspace arena — keep total < ~256 MiB (277 MB crashed; 230 MB runs)
    uint8_t* wp = (uint8_t*)d_ws;
    auto alloc = [&](size_t bytes) {
        void* r = (void*)wp;
        wp += (bytes + 255) & ~(size_t)255;
        return r;
    };
    float*    base   = (float*)alloc((size_t)N_NODES * DD * 4);          // 51.2 MB
    _Float16* Hhi    = (_Float16*)alloc((size_t)N_NODES * DD * 2);       // 25.6 MB
    _Float16* Hlo    = (_Float16*)alloc((size_t)N_NODES * DD * 2);       // 25.6 MB
    _Float16* agghi  = (_Float16*)alloc((size_t)2 * N_NODES * DD * 2);   // 51.2 MB
    _Float16* agglo  = (_Float16*)alloc((size_t)2 * N_NODES * DD * 2);   // 51.2 MB
    _Float16* wthi   = (_Float16*)alloc((size_t)N_LAYERS * 256 * 1792 * 2);  // 7.3 MB
    _Float16* wtlo   = (_Float16*)alloc((size_t)N_LAYERS * 256 * 1792 * 2);  // 7.3 MB
    _Float16* wtg1hi = (_Float16*)alloc((size_t)256 * 256 * 2);
    _Float16* wtg1lo = (_Float16*)alloc((size_t)256 * 256 * 2);
    _Float16* wtg2hi = (_Float16*)alloc((size_t)256 * 256 * 2);
    _Float16* wtg2lo = (_Float16*)alloc((size_t)256 * 256 * 2);
    _Float16* wtf1hi = (_Float16*)alloc((size_t)1024 * 256 * 2);         // 0.5 MB
    _Float16* wtf1lo = (_Float16*)alloc((size_t)1024 * 256 * 2);
    _Float16* wtf2hi = (_Float16*)alloc((size_t)512 * 1024 * 2);         // 1 MB
    _Float16* wtf2lo = (_Float16*)alloc((size_t)512 * 1024 * 2);
    float*    ss4    = (float*)alloc((size_t)N_NODES * 4 * 4);           // 0.8 MB
    float*    pooled = (float*)alloc((size_t)NUM_GRAPHS * DD * 4);
    _Float16* phi    = (_Float16*)alloc((size_t)NUM_GRAPHS * DD * 2);
    _Float16* plo    = (_Float16*)alloc((size_t)NUM_GRAPHS * DD * 2);
    _Float16* z1hi   = (_Float16*)alloc((size_t)NUM_GRAPHS * 1024 * 2);  // 1 MB
    _Float16* z1lo   = (_Float16*)alloc((size_t)NUM_GRAPHS * 1024 * 2);
    _Float16* z2hi   = (_Float16*)alloc((size_t)NUM_GRAPHS * 512 * 2);
    _Float16* z2lo   = (_Float16*)alloc((size_t)NUM_GRAPHS * 512 * 2);
    int*      ioff   = (int*)alloc((size_t)(NKEYS + 1) * 4);
    int*      icur   = (int*)alloc((size_t)NKEYS * 4);
    int*      ibsum  = (int*)alloc(256 * 4);
    int*      isrc   = (int*)alloc((size_t)N_EDGES * 4);
    // total ≈ 236 MB

    const int* src = eidx;
    const int* dst = eidx + N_EDGES;

    // ---- weight prep ----
    const size_t wtot = (size_t)N_LAYERS * 7 * 256 * 256;
    wsplit_rel_kernel<<<(int)((wtot + 255) / 256), 256, 0, stream>>>(rel_W, root_W, wthi, wtlo);
    wsplit_tr_kernel<<<256, 256, 0, stream>>>(gp_W1, wtg1hi, wtg1lo, 256, 256);
    wsplit_tr_kernel<<<256, 256, 0, stream>>>(gp_W2, wtg2hi, wtg2lo, 256, 256);
    wsplit_tr_kernel<<<1024, 256, 0, stream>>>(fc_W1, wtf1hi, wtf1lo, 256, 1024);
    wsplit_tr_kernel<<<2048, 256, 0, stream>>>(fc_W2, wtf2hi, wtf2lo, 1024, 512);

    // ---- CSR build ----
    hipMemsetAsync(icur, 0, (size_t)NKEYS * sizeof(int), stream);
    const int eb = (N_EDGES + 255) / 256;
    hist_kernel<<<eb, 256, 0, stream>>>(dst, etype, icur);
    scan1_kernel<<<SCAN_NB, SCAN_T, 0, stream>>>(icur, ioff, ibsum);
    scan2_kernel<<<1, SCAN_T, 0, stream>>>(ibsum, SCAN_NB);
    scan3_kernel<<<SCAN_NB, SCAN_T, 0, stream>>>(ioff, ibsum);
    hipMemcpyAsync(icur, ioff, (size_t)NKEYS * sizeof(int), hipMemcpyDeviceToDevice, stream);
    csr_fill_kernel<<<eb, 256, 0, stream>>>(src, dst, etype, icur, isrc);

    // ---- encoder ----
    enc_kernel<<<N_NODES, 256, 0, stream>>>(x, enc_W, enc_b, Hhi, Hlo);

    const dim3 gG((N_NODES + 127) / 128, 2);  // 391 x 2
    const int  nodeb = (N_NODES + 3) / 4;
    const int  aggb  = (2 * N_NODES + 3) / 4;  // one wave per (node, rel half)

    for (int L = 0; L < N_LAYERS; ++L) {
        const _Float16* Bh = wthi + (size_t)L * 256 * 1792;
        const _Float16* Bl = wtlo + (size_t)L * 256 * 1792;
        // chunk 1: rels 0,1 (K_agg=512) + root+I via h segment (K=256) + conv_b
        agg2_kernel<<<aggb, 256, 0, stream>>>(Hhi, Hlo, ioff, isrc, agghi, agglo, 0);
        gemm_lds<0><<<gG, 256, 0, stream>>>(agghi, agglo, Hhi, Hlo, Bh, Bl,
                                            256, 1792, 256, 0, 1536, 512, 768,
                                            base, nullptr, nullptr,
                                            conv_b + L * DD, nullptr, nullptr, N_NODES);
        // chunk 2: rels 2,3 accumulate into base
        agg2_kernel<<<aggb, 256, 0, stream>>>(Hhi, Hlo, ioff, isrc, agghi, agglo, 2);
        gemm_lds<3><<<gG, 256, 0, stream>>>(agghi, agglo, Hhi, Hlo, Bh, Bl,
                                            256, 1792, 256, 512, 0, 512, 512,
                                            base, nullptr, nullptr,
                                            nullptr, nullptr, nullptr, N_NODES);
        // chunk 3: rels 4,5 + add base + PReLU -> planes, ss partials
        agg2_kernel<<<aggb, 256, 0, stream>>>(Hhi, Hlo, ioff, isrc, agghi, agglo, 4);
        gemm_lds<1><<<gG, 256, 0, stream>>>(agghi, agglo, Hhi, Hlo, Bh, Bl,
                                            256, 1792, 256, 1024, 0, 512, 512,
                                            base, Hhi, Hlo,
                                            nullptr, prelu_a, ss4, N_NODES);
        // L2-normalize planes
        norm_kernel<<<nodeb, 256, 0, stream>>>(Hhi, Hlo, ss4);
    }

    // gp1 = relu(h @ gp_W1 + gp_b1) -> planes (reuse agg buffers)
    gemm_lds<2><<<gG, 256, 0, stream>>>(nullptr, nullptr, Hhi, Hlo, wtg1hi, wtg1lo,
                                        256, 256, 256, 0, 0, 0, 256,
                                        nullptr, agghi, agglo, gp_b1, nullptr, nullptr, N_NODES);
    // gp2 = gp1 @ gp_W2 + gp_b2 -> base (fp32)
    gemm_lds<0><<<gG, 256, 0, stream>>>(agghi, agglo, nullptr, nullptr, wtg2hi, wtg2lo,
                                        256, 256, 256, 0, 0, 256, 256,
                                        base, nullptr, nullptr, gp_b2, nullptr, nullptr, N_NODES);

    hipMemsetAsync(pooled, 0, (size_t)NUM_GRAPHS * DD * sizeof(float), stream);
    pool_kernel<<<(N_NODES + 127) / 128, 64, 0, stream>>>(base, batch, pooled);
    fsplit_kernel<<<(NUM_GRAPHS * DD + 255) / 256, 256, 0, stream>>>(
        pooled, phi, plo, NUM_GRAPHS * DD);

    // z1 = relu(pooled @ fc_W1 + fc_b1): M=512, K=256, N=1024
    gemm_lds<2><<<dim3(4, 8), 256, 0, stream>>>(nullptr, nullptr, phi, plo, wtf1hi, wtf1lo,
                                                256, 256, 1024, 0, 0, 0, 256,
                                                nullptr, z1hi, z1lo, fc_b1, nullptr, nullptr,
                                                NUM_GRAPHS);
    // z2 = relu(z1 @ fc_W2 + fc_b2): M=512, K=1024, N=512
    gemm_lds<2><<<dim3(4, 4), 256, 0, stream>>>(nullptr, nullptr, z1hi, z1lo, wtf2hi, wtf2lo,
                                                1024, 1024, 512, 0, 0, 0, 1024,
                                                nullptr, z2hi, z2lo, fc_b2, nullptr, nullptr,
                                                NUM_GRAPHS);
    out_kernel<<<NUM_GRAPHS, 64, 0, stream>>>(z2hi, z2lo, out_W, out_b, out);
}

// Round 8
// 3194.235 us; speedup vs baseline: 1.7812x; 1.1373x over previous
//
#include <hip/hip_runtime.h>

#define N_NODES   50000
#define N_EDGES   800000
#define N_REL     6
#define N_LAYERS  8
#define DD        256
#define NUM_GRAPHS 512

#define NKEYS      (N_REL * N_NODES)
#define SCAN_T     256
#define SCAN_E     8
#define SCAN_CHUNK (SCAN_T * SCAN_E)
#define SCAN_NB    ((NKEYS + SCAN_CHUNK - 1) / SCAN_CHUNK)

typedef _Float16 h4 __attribute__((ext_vector_type(4)));
typedef _Float16 h8 __attribute__((ext_vector_type(8)));
typedef float    f4 __attribute__((ext_vector_type(4)));

__device__ __forceinline__ void atomAddF(float* p, float v) { unsafeAtomicAdd(p, v); }

// async global->LDS, 16B per lane. LDS dest = wave-uniform base + lane*16.
__device__ __forceinline__ void load_lds16(const void* g, void* l) {
    __builtin_amdgcn_global_load_lds(
        (const __attribute__((address_space(1))) uint32_t*)g,
        (__attribute__((address_space(3))) uint32_t*)l, 16, 0, 0);
}

// ---------------- encoder: h = x @ enc_W + enc_b, write hi/lo fp16 planes ---
__global__ __launch_bounds__(256) void enc_kernel(const float* __restrict__ x,
                                                  const float* __restrict__ W,
                                                  const float* __restrict__ b,
                                                  _Float16* __restrict__ Hhi,
                                                  _Float16* __restrict__ Hlo) {
    int n = blockIdx.x;
    int d = threadIdx.x;
    float s = b[d];
#pragma unroll
    for (int k = 0; k < 13; ++k) s = fmaf(x[n * 13 + k], W[k * 256 + d], s);
    const _Float16 hi = (_Float16)s;
    Hhi[(size_t)n * DD + d] = hi;
    Hlo[(size_t)n * DD + d] = (_Float16)(s - (float)hi);
}

// ------------- weight split+transpose: rel_W/root_W(+I) -> WT[L][n][1792] ---
__global__ __launch_bounds__(256) void wsplit_rel_kernel(const float* __restrict__ relW,
                                                         const float* __restrict__ rootW,
                                                         _Float16* __restrict__ wthi,
                                                         _Float16* __restrict__ wtlo) {
    const size_t id = (size_t)blockIdx.x * 256 + threadIdx.x;
    if (id >= (size_t)N_LAYERS * 7 * 256 * 256) return;
    const int k = (int)(id & 255);
    const int n = (int)((id >> 8) & 255);
    const int g = (int)((id >> 16) % 7);
    const int L = (int)((id >> 16) / 7);
    float w = (g < 6)
        ? relW[(((size_t)L * 6 + g) * 256 + k) * 256 + n]
        : rootW[((size_t)L * 256 + k) * 256 + n];
    if (g == 6 && k == n) w += 1.0f;  // fold skip: h@(root+I) = h@root + h
    const _Float16 hi = (_Float16)w;
    const size_t o = ((size_t)L * 256 + n) * 1792 + (size_t)g * 256 + k;
    wthi[o] = hi;
    wtlo[o] = (_Float16)(w - (float)hi);
}

// generic [K][N] -> split planes [N][K]
__global__ __launch_bounds__(256) void wsplit_tr_kernel(const float* __restrict__ W,
                                                        _Float16* __restrict__ whi,
                                                        _Float16* __restrict__ wlo,
                                                        int K, int N) {
    const size_t id = (size_t)blockIdx.x * 256 + threadIdx.x;
    if (id >= (size_t)K * N) return;
    const int k = (int)(id % K), n = (int)(id / K);
    const float w = W[(size_t)k * N + n];
    const _Float16 hi = (_Float16)w;
    whi[(size_t)n * K + k] = hi;
    wlo[(size_t)n * K + k] = (_Float16)(w - (float)hi);
}

// split fp32 [M][N] -> hi/lo planes
__global__ __launch_bounds__(256) void fsplit_kernel(const float* __restrict__ S,
                                                     _Float16* __restrict__ hi,
                                                     _Float16* __restrict__ lo, int total) {
    const int id = blockIdx.x * 256 + threadIdx.x;
    if (id >= total) return;
    const float v = S[id];
    const _Float16 h = (_Float16)v;
    hi[id] = h;
    lo[id] = (_Float16)(v - (float)h);
}

// ======= LDS-staged MFMA GEMM: 128x256 tile (full width), BK=32 =============
// 4 waves; wave = wm + 2*wn covers rows [wm*64,+64) x cols [wn*128,+128).
// LDS 48KB (halves): Ah[0,4096) Al[4096,8192) Bh[8192,16384) Bl[16384,24576).
// 16B unit (row,slot): A 512 units/plane, B 1024 units/plane;
// chunk c = slot ^ ((row>>1)&3) (XOR swizzle, same stage & read).
// A = [agg planes (K_agg, plane stride N_NODES*DD, row stride lda) | h seg];
// B planes [n][ldb]; C row stride ldc; grid.y tiles N by 256.
// MODE 0: Cf = acc + bias
// MODE 1: v = acc + Cf; prelu; in-block row L2-norm -> Ohi/Olo planes
// MODE 2: relu(acc + bias) -> Ohi/Olo planes
// MODE 3: Cf += acc
template <int MODE>
__global__ __launch_bounds__(256, 2) void gemm_lds(
    const _Float16* __restrict__ Ahi, const _Float16* __restrict__ Alo,
    const _Float16* __restrict__ Hhi, const _Float16* __restrict__ Hlo,
    const _Float16* __restrict__ Bhi, const _Float16* __restrict__ Blo,
    int lda, int ldb, int ldc, int boff_agg, int boff_h, int K_agg, int K_tot,
    float* __restrict__ Cf, _Float16* __restrict__ Ohi, _Float16* __restrict__ Olo,
    const float* __restrict__ bias, const float* __restrict__ pa, int M) {
    __shared__ _Float16 smem[24576];  // 48 KB
    const int lane = threadIdx.x & 63;
    const int wave = threadIdx.x >> 6;
    const int lm = lane & 15, lq = lane >> 4;
    const int wm = wave & 1, wn = wave >> 1;
    const int mb = blockIdx.x * 128;
    const int nb = blockIdx.y * 256;

    f4 acc[4][8];
#pragma unroll
    for (int i = 0; i < 4; ++i)
#pragma unroll
        for (int j = 0; j < 8; ++j) acc[i][j] = (f4){0.f, 0.f, 0.f, 0.f};

    for (int k0 = 0; k0 < K_tot; k0 += 32) {
        const _Float16 *pAh, *pAl;
        int acol, bcol;
        if (k0 < K_agg) {
            const size_t pb = (size_t)(k0 >> 8) * (size_t)N_NODES * DD;
            pAh = Ahi + pb; pAl = Alo + pb;
            acol = k0 & 255;
            bcol = boff_agg + k0;
        } else {
            pAh = Hhi; pAl = Hlo;
            acol = k0 - K_agg;
            bcol = boff_h + (k0 - K_agg);
        }

        __syncthreads();  // previous tile fully consumed
#pragma unroll
        for (int q = 0; q < 12; ++q) {
            const int ub = (q * 4 + wave) * 64;  // 64-aligned; region fixed per q
            const int u  = ub + lane;
            const _Float16* gp;
            size_t ga;
            if (q < 4) {  // A planes (units 0..1023)
                const int v = u & 511, row = v >> 2, slot = v & 3;
                const int c = slot ^ ((row >> 1) & 3);
                int rg = mb + row; if (rg >= M) rg = M - 1;
                gp = (q < 2) ? pAh : pAl;
                ga = (size_t)rg * lda + acol + c * 8;
            } else {      // B planes (units 1024..3071)
                const int v = u & 1023, row = v >> 2, slot = v & 3;
                const int c = slot ^ ((row >> 1) & 3);
                gp = (q < 8) ? Bhi : Blo;
                ga = (size_t)(nb + row) * ldb + bcol + c * 8;
            }
            load_lds16(gp + ga, smem + (size_t)ub * 8);
        }
        __syncthreads();  // staging drained

        h8 ah[4], al[4], bh[8], bl[8];
#pragma unroll
        for (int i = 0; i < 4; ++i) {
            const int row  = wm * 64 + i * 16 + lm;
            const int slot = lq ^ ((row >> 1) & 3);
            const int o    = (row * 4 + slot) * 8;
            ah[i] = *(const h8*)(smem + o);
            al[i] = *(const h8*)(smem + 4096 + o);
        }
#pragma unroll
        for (int j = 0; j < 8; ++j) {
            const int n    = wn * 128 + j * 16 + lm;
            const int slot = lq ^ ((n >> 1) & 3);
            const int o    = (n * 4 + slot) * 8;
            bh[j] = *(const h8*)(smem + 8192 + o);
            bl[j] = *(const h8*)(smem + 16384 + o);
        }
#pragma unroll
        for (int i = 0; i < 4; ++i)
#pragma unroll
            for (int j = 0; j < 8; ++j) {
                acc[i][j] = __builtin_amdgcn_mfma_f32_16x16x32_f16(ah[i], bh[j], acc[i][j], 0, 0, 0);
                acc[i][j] = __builtin_amdgcn_mfma_f32_16x16x32_f16(ah[i], bl[j], acc[i][j], 0, 0, 0);
                acc[i][j] = __builtin_amdgcn_mfma_f32_16x16x32_f16(al[i], bh[j], acc[i][j], 0, 0, 0);
            }
    }

    if (MODE == 0) {
#pragma unroll
        for (int i = 0; i < 4; ++i)
#pragma unroll
            for (int r = 0; r < 4; ++r) {
                const int row = mb + wm * 64 + i * 16 + lq * 4 + r;
                if (row >= M) continue;
#pragma unroll
                for (int j = 0; j < 8; ++j) {
                    const int col = nb + wn * 128 + j * 16 + lm;
                    Cf[(size_t)row * ldc + col] = acc[i][j][r] + bias[col];
                }
            }
    } else if (MODE == 3) {
#pragma unroll
        for (int i = 0; i < 4; ++i)
#pragma unroll
            for (int r = 0; r < 4; ++r) {
                const int row = mb + wm * 64 + i * 16 + lq * 4 + r;
                if (row >= M) continue;
#pragma unroll
                for (int j = 0; j < 8; ++j) {
                    const int col = nb + wn * 128 + j * 16 + lm;
                    Cf[(size_t)row * ldc + col] += acc[i][j][r];
                }
            }
    } else if (MODE == 2) {
#pragma unroll
        for (int i = 0; i < 4; ++i)
#pragma unroll
            for (int r = 0; r < 4; ++r) {
                const int row = mb + wm * 64 + i * 16 + lq * 4 + r;
                if (row >= M) continue;
#pragma unroll
                for (int j = 0; j < 8; ++j) {
                    const int col = nb + wn * 128 + j * 16 + lm;
                    const float v = fmaxf(acc[i][j][r] + bias[col], 0.f);
                    const _Float16 hi = (_Float16)v;
                    const size_t idx = (size_t)row * ldc + col;
                    Ohi[idx] = hi;
                    Olo[idx] = (_Float16)(v - (float)hi);
                }
            }
    } else {  // MODE 1: add Cf, PReLU, full-row L2-norm in block, write planes
        float* shf = (float*)smem;  // 4 x 64 row partials
        const float a = pa[0];
        __syncthreads();  // done with smem as fp16 staging
#pragma unroll
        for (int i = 0; i < 4; ++i)
#pragma unroll
            for (int r = 0; r < 4; ++r) {
                const int rl  = i * 16 + lq * 4 + r;       // 0..63 within wave's rows
                const int row = mb + wm * 64 + rl;
                float rss = 0.f;
                if (row < M) {
#pragma unroll
                    for (int j = 0; j < 8; ++j) {
                        const int col = nb + wn * 128 + j * 16 + lm;
                        float v = acc[i][j][r] + Cf[(size_t)row * ldc + col];
                        v = v > 0.f ? v : a * v;
                        acc[i][j][r] = v;
                        rss = fmaf(v, v, rss);
                    }
                }
                rss += __shfl_xor(rss, 1, 64);
                rss += __shfl_xor(rss, 2, 64);
                rss += __shfl_xor(rss, 4, 64);
                rss += __shfl_xor(rss, 8, 64);
                if (lm == 0 && row < M) shf[wave * 64 + rl] = rss;
            }
        __syncthreads();
#pragma unroll
        for (int i = 0; i < 4; ++i)
#pragma unroll
            for (int r = 0; r < 4; ++r) {
                const int rl  = i * 16 + lq * 4 + r;
                const int row = mb + wm * 64 + rl;
                if (row >= M) continue;
                const float tot = shf[wm * 64 + rl] + shf[(2 + wm) * 64 + rl];
                const float inv = 1.0f / fmaxf(sqrtf(tot), 1e-12f);
#pragma unroll
                for (int j = 0; j < 8; ++j) {
                    const int col = nb + wn * 128 + j * 16 + lm;
                    const float v = acc[i][j][r] * inv;
                    const _Float16 hi = (_Float16)v;
                    const size_t idx = (size_t)row * ldc + col;
                    Ohi[idx] = hi;
                    Olo[idx] = (_Float16)(v - (float)hi);
                }
            }
    }
}

// ================= CSR build: counting sort by key = rel*N_NODES + dst ======
__global__ __launch_bounds__(256) void hist_kernel(const int* __restrict__ dst,
                                                   const int* __restrict__ etype,
                                                   int* __restrict__ cnt) {
    const int e = blockIdx.x * 256 + threadIdx.x;
    if (e >= N_EDGES) return;
    atomicAdd(&cnt[etype[e] * N_NODES + dst[e]], 1);
}

__global__ __launch_bounds__(SCAN_T) void scan1_kernel(const int* __restrict__ cnt,
                                                       int* __restrict__ off,
                                                       int* __restrict__ bsum) {
    __shared__ int sh[SCAN_T];
    const int b = blockIdx.x, t = threadIdx.x;
    const int base = b * SCAN_CHUNK + t * SCAN_E;
    int pre[SCAN_E];
    int s = 0;
#pragma unroll
    for (int i = 0; i < SCAN_E; ++i) {
        const int x = (base + i < NKEYS) ? cnt[base + i] : 0;
        pre[i] = s;
        s += x;
    }
    sh[t] = s;
    __syncthreads();
    for (int d = 1; d < SCAN_T; d <<= 1) {
        const int x = (t >= d) ? sh[t - d] : 0;
        __syncthreads();
        sh[t] += x;
        __syncthreads();
    }
    const int toff = (t == 0) ? 0 : sh[t - 1];
#pragma unroll
    for (int i = 0; i < SCAN_E; ++i)
        if (base + i < NKEYS) off[base + i] = toff + pre[i];
    if (t == SCAN_T - 1) bsum[b] = sh[SCAN_T - 1];
}

__global__ __launch_bounds__(SCAN_T) void scan2_kernel(int* __restrict__ bsum, int n) {
    __shared__ int sh[SCAN_T];
    const int t = threadIdx.x;
    const int base = t * SCAN_E;
    int pre[SCAN_E];
    int s = 0;
#pragma unroll
    for (int i = 0; i < SCAN_E; ++i) {
        const int x = (base + i < n) ? bsum[base + i] : 0;
        pre[i] = s;
        s += x;
    }
    sh[t] = s;
    __syncthreads();
    for (int d = 1; d < SCAN_T; d <<= 1) {
        const int x = (t >= d) ? sh[t - d] : 0;
        __syncthreads();
        sh[t] += x;
        __syncthreads();
    }
    const int toff = (t == 0) ? 0 : sh[t - 1];
#pragma unroll
    for (int i = 0; i < SCAN_E; ++i)
        if (base + i < n) bsum[base + i] = toff + pre[i];
}

__global__ __launch_bounds__(SCAN_T) void scan3_kernel(int* __restrict__ off,
                                                       const int* __restrict__ bsum) {
    const int b = blockIdx.x, t = threadIdx.x;
    const int add = bsum[b];
    const int base = b * SCAN_CHUNK + t * SCAN_E;
#pragma unroll
    for (int i = 0; i < SCAN_E; ++i)
        if (base + i < NKEYS) off[base + i] += add;
    if (b == 0 && t == 0) off[NKEYS] = N_EDGES;
}

__global__ __launch_bounds__(256) void csr_fill_kernel(const int* __restrict__ src,
                                                       const int* __restrict__ dst,
                                                       const int* __restrict__ etype,
                                                       int* __restrict__ cursor,
                                                       int* __restrict__ sorted_src) {
    const int e = blockIdx.x * 256 + threadIdx.x;
    if (e >= N_EDGES) return;
    const int key = etype[e] * N_NODES + dst[e];
    const int pos = atomicAdd(&cursor[key], 1);
    sorted_src[pos] = src[e];
}

// ---------- aggregation: one wave per (node, rel half); 2 edges/iteration ---
// half-wave h (32 lanes) gathers edge e0+h; lane li covers dims li*8..li*8+8.
__global__ __launch_bounds__(256) void agg2_kernel(const _Float16* __restrict__ Hhi,
                                                   const _Float16* __restrict__ Hlo,
                                                   const int* __restrict__ off,
                                                   const int* __restrict__ isrc,
                                                   _Float16* __restrict__ agghi,
                                                   _Float16* __restrict__ agglo, int rel0) {
    const int pair = blockIdx.x * 4 + (threadIdx.x >> 6);  // 0..2*N_NODES-1
    const int lane = threadIdx.x & 63;
    const int half = lane >> 5, li = lane & 31;
    if (pair >= 2 * N_NODES) return;
    const int rl   = (pair >= N_NODES) ? 1 : 0;
    const int node = pair - rl * N_NODES;
    const int r    = rel0 + rl;
    const int s0 = off[r * N_NODES + node];
    const int s1 = off[r * N_NODES + node + 1];
    float a[8] = {0.f, 0.f, 0.f, 0.f, 0.f, 0.f, 0.f, 0.f};
    for (int e0 = s0; e0 < s1; e0 += 2) {
        const int e = e0 + half;
        if (e < s1) {
            const int s = isrc[e];
            const h8 vh = *(const h8*)(Hhi + (size_t)s * DD + li * 8);
            const h8 vl = *(const h8*)(Hlo + (size_t)s * DD + li * 8);
#pragma unroll
            for (int k = 0; k < 8; ++k) a[k] += (float)vh[k] + (float)vl[k];
        }
    }
#pragma unroll
    for (int k = 0; k < 8; ++k) a[k] += __shfl_xor(a[k], 32, 64);
    if (half == 0) {
        h8 oh, ol;
#pragma unroll
        for (int k = 0; k < 8; ++k) {
            oh[k] = (_Float16)a[k];
            ol[k] = (_Float16)(a[k] - (float)oh[k]);
        }
        const size_t o = ((size_t)rl * N_NODES + node) * DD + li * 8;
        *(h8*)(agghi + o) = oh;
        *(h8*)(agglo + o) = ol;
    }
}

// ---------------- pooled[batch[n]] += g[n]  (batch sorted) ------------------
__global__ __launch_bounds__(64) void pool_kernel(const float* __restrict__ g,
                                                  const int* __restrict__ batch,
                                                  float* __restrict__ pooled) {
    const int c     = threadIdx.x;
    const int start = blockIdx.x * 128;
    const int end   = min(start + 128, N_NODES);
    int cur = batch[start];
    float4 acc = {0.f, 0.f, 0.f, 0.f};
    for (int n = start; n < end; ++n) {
        const int bn = batch[n];
        if (bn != cur) {
            float* p = pooled + (size_t)cur * DD + c * 4;
            atomAddF(p + 0, acc.x); atomAddF(p + 1, acc.y);
            atomAddF(p + 2, acc.z); atomAddF(p + 3, acc.w);
            acc = {0.f, 0.f, 0.f, 0.f};
            cur = bn;
        }
        const float4 v = reinterpret_cast<const float4*>(g + (size_t)n * DD)[c];
        acc.x += v.x; acc.y += v.y; acc.z += v.z; acc.w += v.w;
    }
    float* p = pooled + (size_t)cur * DD + c * 4;
    atomAddF(p + 0, acc.x); atomAddF(p + 1, acc.y);
    atomAddF(p + 2, acc.z); atomAddF(p + 3, acc.w);
}

// ---------------- out = relu((z2hi+z2lo) @ out_W + out_b) -------------------
__global__ __launch_bounds__(64) void out_kernel(const _Float16* __restrict__ z2hi,
                                                 const _Float16* __restrict__ z2lo,
                                                 const float* __restrict__ W,
                                                 const float* __restrict__ b,
                                                 float* __restrict__ out) {
    const int g = blockIdx.x;
    const int t = threadIdx.x;
    float s = 0.f;
#pragma unroll
    for (int j = 0; j < 8; ++j) {
        const int idx = t + 64 * j;
        const float z = (float)z2hi[(size_t)g * 512 + idx] + (float)z2lo[(size_t)g * 512 + idx];
        s = fmaf(z, W[idx], s);
    }
#pragma unroll
    for (int off = 32; off; off >>= 1) s += __shfl_xor(s, off, 64);
    if (t == 0) {
        const float v = s + b[0];
        out[g] = v > 0.f ? v : 0.f;
    }
}

extern "C" void kernel_launch(void* const* d_in, const int* in_sizes, int n_in,
                              void* d_out, int out_size, void* d_ws, size_t ws_size,
                              hipStream_t stream) {
    const float* x       = (const float*)d_in[0];
    const int*   eidx    = (const int*)d_in[1];
    const int*   etype   = (const int*)d_in[2];
    const int*   batch   = (const int*)d_in[3];
    const float* enc_W   = (const float*)d_in[4];
    const float* enc_b   = (const float*)d_in[5];
    const float* prelu_a = (const float*)d_in[6];
    const float* rel_W   = (const float*)d_in[7];
    const float* root_W  = (const float*)d_in[8];
    const float* conv_b  = (const float*)d_in[9];
    const float* gp_W1   = (const float*)d_in[10];
    const float* gp_b1   = (const float*)d_in[11];
    const float* gp_W2   = (const float*)d_in[12];
    const float* gp_b2   = (const float*)d_in[13];
    const float* fc_W1   = (const float*)d_in[14];
    const float* fc_b1   = (const float*)d_in[15];
    const float* fc_W2   = (const float*)d_in[16];
    const float* fc_b2   = (const float*)d_in[17];
    const float* out_W   = (const float*)d_in[18];
    const float* out_b   = (const float*)d_in[19];
    float* out = (float*)d_out;

    // workspace arena — keep total < ~256 MiB (277 MB crashed; 236 MB runs)
    uint8_t* wp = (uint8_t*)d_ws;
    auto alloc = [&](size_t bytes) {
        void* r = (void*)wp;
        wp += (bytes + 255) & ~(size_t)255;
        return r;
    };
    float*    base   = (float*)alloc((size_t)N_NODES * DD * 4);          // 51.2 MB
    _Float16* Hhi    = (_Float16*)alloc((size_t)N_NODES * DD * 2);       // 25.6 MB
    _Float16* Hlo    = (_Float16*)alloc((size_t)N_NODES * DD * 2);       // 25.6 MB
    _Float16* agghi  = (_Float16*)alloc((size_t)2 * N_NODES * DD * 2);   // 51.2 MB
    _Float16* agglo  = (_Float16*)alloc((size_t)2 * N_NODES * DD * 2);   // 51.2 MB
    _Float16* wthi   = (_Float16*)alloc((size_t)N_LAYERS * 256 * 1792 * 2);  // 7.3 MB
    _Float16* wtlo   = (_Float16*)alloc((size_t)N_LAYERS * 256 * 1792 * 2);  // 7.3 MB
    _Float16* wtg1hi = (_Float16*)alloc((size_t)256 * 256 * 2);
    _Float16* wtg1lo = (_Float16*)alloc((size_t)256 * 256 * 2);
    _Float16* wtg2hi = (_Float16*)alloc((size_t)256 * 256 * 2);
    _Float16* wtg2lo = (_Float16*)alloc((size_t)256 * 256 * 2);
    _Float16* wtf1hi = (_Float16*)alloc((size_t)1024 * 256 * 2);
    _Float16* wtf1lo = (_Float16*)alloc((size_t)1024 * 256 * 2);
    _Float16* wtf2hi = (_Float16*)alloc((size_t)512 * 1024 * 2);
    _Float16* wtf2lo = (_Float16*)alloc((size_t)512 * 1024 * 2);
    float*    pooled = (float*)alloc((size_t)NUM_GRAPHS * DD * 4);
    _Float16* phi    = (_Float16*)alloc((size_t)NUM_GRAPHS * DD * 2);
    _Float16* plo    = (_Float16*)alloc((size_t)NUM_GRAPHS * DD * 2);
    _Float16* z1hi   = (_Float16*)alloc((size_t)NUM_GRAPHS * 1024 * 2);
    _Float16* z1lo   = (_Float16*)alloc((size_t)NUM_GRAPHS * 1024 * 2);
    _Float16* z2hi   = (_Float16*)alloc((size_t)NUM_GRAPHS * 512 * 2);
    _Float16* z2lo   = (_Float16*)alloc((size_t)NUM_GRAPHS * 512 * 2);
    int*      ioff   = (int*)alloc((size_t)(NKEYS + 1) * 4);
    int*      icur   = (int*)alloc((size_t)NKEYS * 4);
    int*      ibsum  = (int*)alloc(256 * 4);
    int*      isrc   = (int*)alloc((size_t)N_EDGES * 4);
    // total ≈ 235 MB

    const int* src = eidx;
    const int* dst = eidx + N_EDGES;

    // ---- weight prep ----
    const size_t wtot = (size_t)N_LAYERS * 7 * 256 * 256;
    wsplit_rel_kernel<<<(int)((wtot + 255) / 256), 256, 0, stream>>>(rel_W, root_W, wthi, wtlo);
    wsplit_tr_kernel<<<256, 256, 0, stream>>>(gp_W1, wtg1hi, wtg1lo, 256, 256);
    wsplit_tr_kernel<<<256, 256, 0, stream>>>(gp_W2, wtg2hi, wtg2lo, 256, 256);
    wsplit_tr_kernel<<<1024, 256, 0, stream>>>(fc_W1, wtf1hi, wtf1lo, 256, 1024);
    wsplit_tr_kernel<<<2048, 256, 0, stream>>>(fc_W2, wtf2hi, wtf2lo, 1024, 512);

    // ---- CSR build ----
    hipMemsetAsync(icur, 0, (size_t)NKEYS * sizeof(int), stream);
    const int eb = (N_EDGES + 255) / 256;
    hist_kernel<<<eb, 256, 0, stream>>>(dst, etype, icur);
    scan1_kernel<<<SCAN_NB, SCAN_T, 0, stream>>>(icur, ioff, ibsum);
    scan2_kernel<<<1, SCAN_T, 0, stream>>>(ibsum, SCAN_NB);
    scan3_kernel<<<SCAN_NB, SCAN_T, 0, stream>>>(ioff, ibsum);
    hipMemcpyAsync(icur, ioff, (size_t)NKEYS * sizeof(int), hipMemcpyDeviceToDevice, stream);
    csr_fill_kernel<<<eb, 256, 0, stream>>>(src, dst, etype, icur, isrc);

    // ---- encoder ----
    enc_kernel<<<N_NODES, 256, 0, stream>>>(x, enc_W, enc_b, Hhi, Hlo);

    const dim3 gG((N_NODES + 127) / 128, 1);   // 391 x 1 — full-width tiles
    const int  aggb = (2 * N_NODES + 3) / 4;   // one wave per (node, rel half)

    for (int L = 0; L < N_LAYERS; ++L) {
        const _Float16* Bh = wthi + (size_t)L * 256 * 1792;
        const _Float16* Bl = wtlo + (size_t)L * 256 * 1792;
        // chunk 1: rels 0,1 (K_agg=512) + root+I via h segment (K=256) + conv_b
        agg2_kernel<<<aggb, 256, 0, stream>>>(Hhi, Hlo, ioff, isrc, agghi, agglo, 0);
        gemm_lds<0><<<gG, 256, 0, stream>>>(agghi, agglo, Hhi, Hlo, Bh, Bl,
                                            256, 1792, 256, 0, 1536, 512, 768,
                                            base, nullptr, nullptr,
                                            conv_b + L * DD, nullptr, N_NODES);
        // chunk 2: rels 2,3 accumulate into base
        agg2_kernel<<<aggb, 256, 0, stream>>>(Hhi, Hlo, ioff, isrc, agghi, agglo, 2);
        gemm_lds<3><<<gG, 256, 0, stream>>>(agghi, agglo, Hhi, Hlo, Bh, Bl,
                                            256, 1792, 256, 512, 0, 512, 512,
                                            base, nullptr, nullptr,
                                            nullptr, nullptr, N_NODES);
        // chunk 3: rels 4,5 + add base + PReLU + in-block L2-norm -> new planes
        agg2_kernel<<<aggb, 256, 0, stream>>>(Hhi, Hlo, ioff, isrc, agghi, agglo, 4);
        gemm_lds<1><<<gG, 256, 0, stream>>>(agghi, agglo, Hhi, Hlo, Bh, Bl,
                                            256, 1792, 256, 1024, 0, 512, 512,
                                            base, Hhi, Hlo,
                                            nullptr, prelu_a, N_NODES);
    }

    // gp1 = relu(h @ gp_W1 + gp_b1) -> planes (reuse agg buffers)
    gemm_lds<2><<<gG, 256, 0, stream>>>(nullptr, nullptr, Hhi, Hlo, wtg1hi, wtg1lo,
                                        256, 256, 256, 0, 0, 0, 256,
                                        nullptr, agghi, agglo, gp_b1, nullptr, N_NODES);
    // gp2 = gp1 @ gp_W2 + gp_b2 -> base (fp32)
    gemm_lds<0><<<gG, 256, 0, stream>>>(agghi, agglo, nullptr, nullptr, wtg2hi, wtg2lo,
                                        256, 256, 256, 0, 0, 256, 256,
                                        base, nullptr, nullptr, gp_b2, nullptr, N_NODES);

    hipMemsetAsync(pooled, 0, (size_t)NUM_GRAPHS * DD * sizeof(float), stream);
    pool_kernel<<<(N_NODES + 127) / 128, 64, 0, stream>>>(base, batch, pooled);
    fsplit_kernel<<<(NUM_GRAPHS * DD + 255) / 256, 256, 0, stream>>>(
        pooled, phi, plo, NUM_GRAPHS * DD);

    // z1 = relu(pooled @ fc_W1 + fc_b1): M=512, K=256, N=1024
    gemm_lds<2><<<dim3(4, 4), 256, 0, stream>>>(nullptr, nullptr, phi, plo, wtf1hi, wtf1lo,
                                                256, 256, 1024, 0, 0, 0, 256,
                                                nullptr, z1hi, z1lo, fc_b1, nullptr,
                                                NUM_GRAPHS);
    // z2 = relu(z1 @ fc_W2 + fc_b2): M=512, K=1024, N=512
    gemm_lds<2><<<dim3(4, 2), 256, 0, stream>>>(nullptr, nullptr, z1hi, z1lo, wtf2hi, wtf2lo,
                                                1024, 1024, 512, 0, 0, 0, 1024,
                                                nullptr, z2hi, z2lo, fc_b2, nullptr,
                                                NUM_GRAPHS);
    out_kernel<<<NUM_GRAPHS, 64, 0, stream>>>(z2hi, z2lo, out_W, out_b, out);
}